// Round 1
// baseline (941.625 us; speedup 1.0000x reference)
//
#include <hip/hip_runtime.h>
#include <hip/hip_bf16.h>

#define N_NODES 50000
#define DIN     256
#define DOUT    128
#define NCLS    2
#define NHOP    2
#define NDEV    3
#define EDG     500000
#define TE      (NDEV*EDG)
#define NMASK   10000

__device__ __forceinline__ float softplusf(float a) {
    // log(1 + e^a), stable
    return fmaxf(a, 0.f) + log1pf(expf(-fabsf(a)));
}

// ---------------- CSR build ----------------

__global__ void k_hist(const int* __restrict__ dst, int* __restrict__ counts, int total) {
    int i = blockIdx.x * blockDim.x + threadIdx.x;
    if (i < total) atomicAdd(&counts[dst[i]], 1);
}

__global__ void k_scan1(const int* __restrict__ counts, int* __restrict__ offs,
                        int* __restrict__ bsums, int n) {
    __shared__ int s[256];
    int tid = threadIdx.x;
    int gid = blockIdx.x * 256 + tid;
    int v = (gid < n) ? counts[gid] : 0;
    s[tid] = v; __syncthreads();
    for (int o = 1; o < 256; o <<= 1) {
        int t = (tid >= o) ? s[tid - o] : 0;
        __syncthreads();
        s[tid] += t;
        __syncthreads();
    }
    if (gid < n) offs[gid + 1] = s[tid];
    if (tid == 255) bsums[blockIdx.x] = s[255];
}

__global__ void k_scan2(int* __restrict__ bsums, int nb) {
    __shared__ int s[256];
    int tid = threadIdx.x;
    int v = (tid < nb) ? bsums[tid] : 0;
    s[tid] = v; __syncthreads();
    for (int o = 1; o < 256; o <<= 1) {
        int t = (tid >= o) ? s[tid - o] : 0;
        __syncthreads();
        s[tid] += t;
        __syncthreads();
    }
    if (tid < nb) bsums[tid] = s[tid];  // inclusive
}

__global__ void k_scan3(int* __restrict__ offs, const int* __restrict__ bsums, int n) {
    int gid = blockIdx.x * 256 + threadIdx.x;
    if (gid == 0) offs[0] = 0;
    if (gid < n && blockIdx.x > 0) offs[gid + 1] += bsums[blockIdx.x - 1];
}

__global__ void k_scatter(const int* __restrict__ src, const int* __restrict__ dst,
                          const float* __restrict__ vals, const int* __restrict__ offs,
                          int* __restrict__ cur, unsigned* __restrict__ eSrc,
                          float* __restrict__ eVal, int total) {
    int i = blockIdx.x * blockDim.x + threadIdx.x;
    if (i >= total) return;
    int d = i / EDG;                 // device id
    int n = dst[i];
    int pos = offs[n] + atomicAdd(&cur[n], 1);
    eSrc[pos] = ((unsigned)src[i]) | ((unsigned)d << 16);  // src < 50000 < 2^16
    eVal[pos] = vals[i];
}

// ---------------- sparse aggregation (CSR, no atomics) ----------------
// aggc[n][t] = sum over edges e with dst==n of alpha[dev_e]*val_e * h[src_e][t]
__global__ __launch_bounds__(128) void k_agg(const float* __restrict__ h,
                                             const unsigned* __restrict__ eSrc,
                                             const float* __restrict__ eVal,
                                             const int* __restrict__ offs,
                                             const float* __restrict__ alpha_hop,
                                             float* __restrict__ aggc) {
    int n = blockIdx.x;
    int t = threadIdx.x;  // 128 threads = one column each
    float a0 = alpha_hop[0], a1 = alpha_hop[1], a2 = alpha_hop[2];
    int beg = offs[n], end = offs[n + 1];
    float acc = 0.f;
    for (int e = beg; e < end; ++e) {
        unsigned m = eSrc[e];
        float v = eVal[e];
        int s = (int)(m & 0xFFFFu);
        int d = (int)(m >> 16);
        float al = (d == 0) ? a0 : ((d == 1) ? a1 : a2);
        acc += (al * v) * h[(size_t)s * DOUT + t];
    }
    aggc[(size_t)n * DOUT + t] = acc;
}

// ---------------- fp32 tiled GEMM: C[M][128] = A[M][K] @ B[K][128] (+addin, sigmoid) ----
// BM=64, BN=128(full), BK=32, 256 threads, 8x4 micro-tile per thread.
__global__ __launch_bounds__(256) void k_gemm(const float* __restrict__ A,
                                              const float* __restrict__ B,
                                              float* __restrict__ C,
                                              const float* __restrict__ addin,
                                              int M, int K, int sig) {
    __shared__ float As[32][68];    // transposed: As[k][m], pad 68 for bank spread + 16B align
    __shared__ float Bs[32][128];
    int tid = threadIdx.x;
    int tx = tid & 31;   // cols tx*4 .. +3
    int ty = tid >> 5;   // rows ty*8 .. +7
    int row0 = blockIdx.x * 64;

    float acc[8][4];
#pragma unroll
    for (int r = 0; r < 8; ++r)
#pragma unroll
        for (int c = 0; c < 4; ++c) acc[r][c] = 0.f;

    int lr = tid >> 2;          // 0..63 : A row within tile
    int lk = (tid & 3) * 8;     // 0,8,16,24 : k start (8 consecutive floats)

    for (int k0 = 0; k0 < K; k0 += 32) {
        // load A tile (transposed into LDS)
        float4 a0v = make_float4(0, 0, 0, 0), a1v = make_float4(0, 0, 0, 0);
        int arow = row0 + lr;
        if (arow < M) {
            const float4* ap = (const float4*)(A + (size_t)arow * K + k0 + lk);
            a0v = ap[0];
            a1v = ap[1];
        }
        {
            float av[8] = {a0v.x, a0v.y, a0v.z, a0v.w, a1v.x, a1v.y, a1v.z, a1v.w};
#pragma unroll
            for (int j = 0; j < 8; ++j) As[lk + j][lr] = av[j];
        }
        // load B tile: 32x128 floats = 1024 float4, 4 per thread
#pragma unroll
        for (int j = 0; j < 4; ++j) {
            int fidx = tid + j * 256;
            int kk = fidx >> 5;
            int c4 = fidx & 31;
            float4 g = ((const float4*)B)[(size_t)(k0 + kk) * 32 + c4];
            *(float4*)&Bs[kk][c4 * 4] = g;
        }
        __syncthreads();

#pragma unroll
        for (int kk = 0; kk < 32; ++kk) {
            float4 bA = *(const float4*)&Bs[kk][tx * 4];
            float4 aA = *(const float4*)&As[kk][ty * 8];
            float4 aB = *(const float4*)&As[kk][ty * 8 + 4];
            float ar[8] = {aA.x, aA.y, aA.z, aA.w, aB.x, aB.y, aB.z, aB.w};
            float bc[4] = {bA.x, bA.y, bA.z, bA.w};
#pragma unroll
            for (int r = 0; r < 8; ++r)
#pragma unroll
                for (int c = 0; c < 4; ++c) acc[r][c] += ar[r] * bc[c];
        }
        __syncthreads();
    }

#pragma unroll
    for (int r = 0; r < 8; ++r) {
        int row = row0 + ty * 8 + r;
        if (row < M) {
            float4 v = make_float4(acc[r][0], acc[r][1], acc[r][2], acc[r][3]);
            size_t o = (size_t)row * DOUT + tx * 4;
            if (addin) {
                float4 ad = *(const float4*)(addin + o);
                v.x += ad.x; v.y += ad.y; v.z += ad.z; v.w += ad.w;
            }
            if (sig) {
                v.x = 1.f / (1.f + expf(-v.x));
                v.y = 1.f / (1.f + expf(-v.y));
                v.z = 1.f / (1.f + expf(-v.z));
                v.w = 1.f / (1.f + expf(-v.w));
            }
            *(float4*)(C + o) = v;
        }
    }
}

// ---------------- masked loss + accuracy ----------------
__global__ __launch_bounds__(256) void k_loss(const float* __restrict__ h,
                                              const float* __restrict__ label,
                                              const int* __restrict__ idx,
                                              const float* __restrict__ u,
                                              const float* __restrict__ Wc,
                                              const float* __restrict__ bb,
                                              float* __restrict__ partials, int Mtot) {
    int w = (blockIdx.x * blockDim.x + threadIdx.x) >> 6;
    int lane = threadIdx.x & 63;
    if (w >= Mtot) return;
    int node = idx[w];
    float v0 = h[(size_t)node * DOUT + lane];
    float v1 = h[(size_t)node * DOUT + 64 + lane];
    float ps = v0 * u[lane] + v1 * u[64 + lane];
    float p0 = v0 * Wc[lane * 2 + 0] + v1 * Wc[(lane + 64) * 2 + 0];
    float p1 = v0 * Wc[lane * 2 + 1] + v1 * Wc[(lane + 64) * 2 + 1];
#pragma unroll
    for (int o = 32; o > 0; o >>= 1) {
        ps += __shfl_xor(ps, o, 64);
        p0 += __shfl_xor(p0, o, 64);
        p1 += __shfl_xor(p1, o, 64);
    }
    if (lane == 0) {
        float score = ps;
        float y0 = label[(size_t)node * NCLS + 0];
        float y1 = label[(size_t)node * NCLS + 1];
        float loss = softplusf(-(y0 * score)) + softplusf(-(y1 * score));
        float l0 = p0 + bb[0], l1 = p1 + bb[1];
        int pred = (l1 > l0) ? 1 : 0;
        int truth = (y1 > y0) ? 1 : 0;
        float corr = (pred == truth) ? 1.f : 0.f;
        atomicAdd(&partials[0], loss);
        atomicAdd(&partials[1], corr);
    }
}

__global__ void k_final(const float* __restrict__ partials, float* __restrict__ out) {
    out[0] = partials[0];
    out[1] = partials[1] * (1.0f / NMASK);
}

// ---------------- launch ----------------
extern "C" void kernel_launch(void* const* d_in, const int* in_sizes, int n_in,
                              void* d_out, int out_size, void* d_ws, size_t ws_size,
                              hipStream_t stream) {
    const float* x      = (const float*)d_in[0];
    const float* label  = (const float*)d_in[1];
    const int*   idx    = (const int*)d_in[2];
    const int*   src    = (const int*)d_in[3];
    const int*   dst    = (const int*)d_in[4];
    const float* vals   = (const float*)d_in[5];
    const float* h0     = (const float*)d_in[6];
    const float* Ws     = (const float*)d_in[7];
    const float* Vs     = (const float*)d_in[8];
    const float* alphas = (const float*)d_in[9];
    const float* Wc     = (const float*)d_in[10];
    const float* bb     = (const float*)d_in[11];
    const float* u      = (const float*)d_in[12];
    float* out = (float*)d_out;

    char* p = (char*)d_ws;
    float*    hB    = (float*)p;    p += (size_t)N_NODES * DOUT * 4;   // 25.6 MB
    float*    aggc  = (float*)p;    p += (size_t)N_NODES * DOUT * 4;   // 25.6 MB
    unsigned* eSrc  = (unsigned*)p; p += (size_t)TE * 4;               // 6 MB
    float*    eVal  = (float*)p;    p += (size_t)TE * 4;               // 6 MB
    int*      counts= (int*)p;      p += 200064;
    int*      offs  = (int*)p;      p += 200064;                        // N+1 ints
    int*      bsums = (int*)p;      p += 1024;
    float*    partials = (float*)p; p += 256;

    const int NB = (N_NODES + 255) / 256;  // 196

    // CSR build (reused for both hops; per-hop alpha applied at read time)
    hipMemsetAsync(counts, 0, (size_t)N_NODES * 4, stream);
    k_hist<<<(TE + 255) / 256, 256, 0, stream>>>(dst, counts, TE);
    k_scan1<<<NB, 256, 0, stream>>>(counts, offs, bsums, N_NODES);
    k_scan2<<<1, 256, 0, stream>>>(bsums, NB);
    k_scan3<<<NB, 256, 0, stream>>>(offs, bsums, N_NODES);
    hipMemsetAsync(counts, 0, (size_t)N_NODES * 4, stream);
    k_scatter<<<(TE + 255) / 256, 256, 0, stream>>>(src, dst, vals, offs, counts, eSrc, eVal, TE);

    const int GBLK = (N_NODES + 63) / 64;  // 782
    for (int hop = 0; hop < NHOP; ++hop) {
        const float* hcur = hop ? (const float*)hB : h0;
        k_agg<<<N_NODES, 128, 0, stream>>>(hcur, eSrc, eVal, offs, alphas + hop * NDEV, aggc);
        // h1 = x @ Ws[hop] -> hB   (safe: agg already consumed old h)
        k_gemm<<<GBLK, 256, 0, stream>>>(x, Ws + (size_t)hop * DIN * DOUT, hB, nullptr,
                                         N_NODES, DIN, 0);
        // hB = sigmoid(hB + aggc @ Vs[hop])
        k_gemm<<<GBLK, 256, 0, stream>>>(aggc, Vs + (size_t)hop * DOUT * DOUT, hB, hB,
                                         N_NODES, DOUT, 1);
    }

    hipMemsetAsync(partials, 0, 8, stream);
    k_loss<<<(NMASK * 64 + 255) / 256, 256, 0, stream>>>(hB, label, idx, u, Wc, bb,
                                                         partials, NMASK);
    k_final<<<1, 1, 0, stream>>>(partials, out);
}

// Round 2
// 741.010 us; speedup vs baseline: 1.2707x; 1.2707x over previous
//
#include <hip/hip_runtime.h>
#include <hip/hip_bf16.h>

#define N_NODES 50000
#define DIN     256
#define DOUT    128
#define NCLS    2
#define NHOP    2
#define NDEV    3
#define EDG     500000
#define TE      (NDEV*EDG)
#define NMASK   10000
#define LOSS_BLOCKS 100

__device__ __forceinline__ float softplusf(float a) {
    // log(1 + e^a), stable
    return fmaxf(a, 0.f) + log1pf(expf(-fabsf(a)));
}

// ---------------- CSR build ----------------

__global__ void k_hist(const int* __restrict__ dst, int* __restrict__ counts, int total) {
    int i = blockIdx.x * blockDim.x + threadIdx.x;
    if (i < total) atomicAdd(&counts[dst[i]], 1);
}

__global__ void k_scan1(const int* __restrict__ counts, int* __restrict__ offs,
                        int* __restrict__ bsums, int n) {
    __shared__ int s[256];
    int tid = threadIdx.x;
    int gid = blockIdx.x * 256 + tid;
    int v = (gid < n) ? counts[gid] : 0;
    s[tid] = v; __syncthreads();
    for (int o = 1; o < 256; o <<= 1) {
        int t = (tid >= o) ? s[tid - o] : 0;
        __syncthreads();
        s[tid] += t;
        __syncthreads();
    }
    if (gid < n) offs[gid + 1] = s[tid];
    if (tid == 255) bsums[blockIdx.x] = s[255];
}

__global__ void k_scan2(int* __restrict__ bsums, int nb) {
    __shared__ int s[256];
    int tid = threadIdx.x;
    int v = (tid < nb) ? bsums[tid] : 0;
    s[tid] = v; __syncthreads();
    for (int o = 1; o < 256; o <<= 1) {
        int t = (tid >= o) ? s[tid - o] : 0;
        __syncthreads();
        s[tid] += t;
        __syncthreads();
    }
    if (tid < nb) bsums[tid] = s[tid];  // inclusive
}

__global__ void k_scan3(int* __restrict__ offs, const int* __restrict__ bsums, int n) {
    int gid = blockIdx.x * 256 + threadIdx.x;
    if (gid == 0) offs[0] = 0;
    if (gid < n && blockIdx.x > 0) offs[gid + 1] += bsums[blockIdx.x - 1];
}

__global__ void k_scatter(const int* __restrict__ src, const int* __restrict__ dst,
                          const float* __restrict__ vals, const int* __restrict__ offs,
                          int* __restrict__ cur, unsigned* __restrict__ eSrc,
                          float* __restrict__ eVal, int total) {
    int i = blockIdx.x * blockDim.x + threadIdx.x;
    if (i >= total) return;
    int d = i / EDG;                 // device id
    int n = dst[i];
    int pos = offs[n] + atomicAdd(&cur[n], 1);
    eSrc[pos] = ((unsigned)src[i]) | ((unsigned)d << 16);  // src < 50000 < 2^16
    eVal[pos] = vals[i];
}

// ---------------- sparse aggregation (CSR, no atomics) ----------------
__global__ __launch_bounds__(128) void k_agg(const float* __restrict__ h,
                                             const unsigned* __restrict__ eSrc,
                                             const float* __restrict__ eVal,
                                             const int* __restrict__ offs,
                                             const float* __restrict__ alpha_hop,
                                             float* __restrict__ aggc) {
    int n = blockIdx.x;
    int t = threadIdx.x;  // 128 threads = one column each
    float a0 = alpha_hop[0], a1 = alpha_hop[1], a2 = alpha_hop[2];
    int beg = offs[n], end = offs[n + 1];
    float acc = 0.f;
    for (int e = beg; e < end; ++e) {
        unsigned m = eSrc[e];
        float v = eVal[e];
        int s = (int)(m & 0xFFFFu);
        int d = (int)(m >> 16);
        float al = (d == 0) ? a0 : ((d == 1) ? a1 : a2);
        acc += (al * v) * h[(size_t)s * DOUT + t];
    }
    aggc[(size_t)n * DOUT + t] = acc;
}

// ---------------- fp32 tiled GEMM ----------------
__global__ __launch_bounds__(256) void k_gemm(const float* __restrict__ A,
                                              const float* __restrict__ B,
                                              float* __restrict__ C,
                                              const float* __restrict__ addin,
                                              int M, int K, int sig) {
    __shared__ float As[32][68];
    __shared__ float Bs[32][128];
    int tid = threadIdx.x;
    int tx = tid & 31;
    int ty = tid >> 5;
    int row0 = blockIdx.x * 64;

    float acc[8][4];
#pragma unroll
    for (int r = 0; r < 8; ++r)
#pragma unroll
        for (int c = 0; c < 4; ++c) acc[r][c] = 0.f;

    int lr = tid >> 2;
    int lk = (tid & 3) * 8;

    for (int k0 = 0; k0 < K; k0 += 32) {
        float4 a0v = make_float4(0, 0, 0, 0), a1v = make_float4(0, 0, 0, 0);
        int arow = row0 + lr;
        if (arow < M) {
            const float4* ap = (const float4*)(A + (size_t)arow * K + k0 + lk);
            a0v = ap[0];
            a1v = ap[1];
        }
        {
            float av[8] = {a0v.x, a0v.y, a0v.z, a0v.w, a1v.x, a1v.y, a1v.z, a1v.w};
#pragma unroll
            for (int j = 0; j < 8; ++j) As[lk + j][lr] = av[j];
        }
#pragma unroll
        for (int j = 0; j < 4; ++j) {
            int fidx = tid + j * 256;
            int kk = fidx >> 5;
            int c4 = fidx & 31;
            float4 g = ((const float4*)B)[(size_t)(k0 + kk) * 32 + c4];
            *(float4*)&Bs[kk][c4 * 4] = g;
        }
        __syncthreads();

#pragma unroll
        for (int kk = 0; kk < 32; ++kk) {
            float4 bA = *(const float4*)&Bs[kk][tx * 4];
            float4 aA = *(const float4*)&As[kk][ty * 8];
            float4 aB = *(const float4*)&As[kk][ty * 8 + 4];
            float ar[8] = {aA.x, aA.y, aA.z, aA.w, aB.x, aB.y, aB.z, aB.w};
            float bc[4] = {bA.x, bA.y, bA.z, bA.w};
#pragma unroll
            for (int r = 0; r < 8; ++r)
#pragma unroll
                for (int c = 0; c < 4; ++c) acc[r][c] += ar[r] * bc[c];
        }
        __syncthreads();
    }

#pragma unroll
    for (int r = 0; r < 8; ++r) {
        int row = row0 + ty * 8 + r;
        if (row < M) {
            float4 v = make_float4(acc[r][0], acc[r][1], acc[r][2], acc[r][3]);
            size_t o = (size_t)row * DOUT + tx * 4;
            if (addin) {
                float4 ad = *(const float4*)(addin + o);
                v.x += ad.x; v.y += ad.y; v.z += ad.z; v.w += ad.w;
            }
            if (sig) {
                v.x = 1.f / (1.f + expf(-v.x));
                v.y = 1.f / (1.f + expf(-v.y));
                v.z = 1.f / (1.f + expf(-v.z));
                v.w = 1.f / (1.f + expf(-v.w));
            }
            *(float4*)(C + o) = v;
        }
    }
}

// ---------------- masked loss + accuracy (no global atomics) ----------------
// 100 blocks x 4 waves; each wave grid-strides masked nodes; block writes one
// (loss, correct) pair to blockpart; k_final reduces the 100 pairs.
__global__ __launch_bounds__(256) void k_loss(const float* __restrict__ h,
                                              const float* __restrict__ label,
                                              const int* __restrict__ idx,
                                              const float* __restrict__ u,
                                              const float* __restrict__ Wc,
                                              const float* __restrict__ bb,
                                              float* __restrict__ blockpart, int Mtot) {
    __shared__ float sl[4], sc[4];
    int wid = threadIdx.x >> 6;
    int lane = threadIdx.x & 63;
    int gw = blockIdx.x * 4 + wid;
    int nw = gridDim.x * 4;
    float uv0 = u[lane], uv1 = u[64 + lane];
    float wc00 = Wc[lane * 2 + 0], wc01 = Wc[lane * 2 + 1];
    float wc10 = Wc[(lane + 64) * 2 + 0], wc11 = Wc[(lane + 64) * 2 + 1];
    float b0 = bb[0], b1 = bb[1];
    float lsum = 0.f, csum = 0.f;
    for (int w = gw; w < Mtot; w += nw) {
        int node = idx[w];
        float v0 = h[(size_t)node * DOUT + lane];
        float v1 = h[(size_t)node * DOUT + 64 + lane];
        float ps = v0 * uv0 + v1 * uv1;
        float p0 = v0 * wc00 + v1 * wc10;
        float p1 = v0 * wc01 + v1 * wc11;
#pragma unroll
        for (int o = 32; o > 0; o >>= 1) {
            ps += __shfl_xor(ps, o, 64);
            p0 += __shfl_xor(p0, o, 64);
            p1 += __shfl_xor(p1, o, 64);
        }
        if (lane == 0) {
            float y0 = label[(size_t)node * NCLS + 0];
            float y1 = label[(size_t)node * NCLS + 1];
            lsum += softplusf(-(y0 * ps)) + softplusf(-(y1 * ps));
            float l0 = p0 + b0, l1 = p1 + b1;
            int pred = (l1 > l0) ? 1 : 0;
            int truth = (y1 > y0) ? 1 : 0;
            csum += (pred == truth) ? 1.f : 0.f;
        }
    }
    if (lane == 0) { sl[wid] = lsum; sc[wid] = csum; }
    __syncthreads();
    if (threadIdx.x == 0) {
        blockpart[blockIdx.x * 2 + 0] = sl[0] + sl[1] + sl[2] + sl[3];
        blockpart[blockIdx.x * 2 + 1] = sc[0] + sc[1] + sc[2] + sc[3];
    }
}

__global__ __launch_bounds__(256) void k_final(const float* __restrict__ bp,
                                               float* __restrict__ out, int nb) {
    __shared__ float sl[256], sc[256];
    int t = threadIdx.x;
    float l = 0.f, c = 0.f;
    for (int i = t; i < nb; i += 256) { l += bp[i * 2]; c += bp[i * 2 + 1]; }
    sl[t] = l; sc[t] = c;
    __syncthreads();
    for (int o = 128; o > 0; o >>= 1) {
        if (t < o) { sl[t] += sl[t + o]; sc[t] += sc[t + o]; }
        __syncthreads();
    }
    if (t == 0) { out[0] = sl[0]; out[1] = sc[0] * (1.0f / NMASK); }
}

// ---------------- launch ----------------
extern "C" void kernel_launch(void* const* d_in, const int* in_sizes, int n_in,
                              void* d_out, int out_size, void* d_ws, size_t ws_size,
                              hipStream_t stream) {
    const float* x      = (const float*)d_in[0];
    const float* label  = (const float*)d_in[1];
    const int*   idx    = (const int*)d_in[2];
    const int*   src    = (const int*)d_in[3];
    const int*   dst    = (const int*)d_in[4];
    const float* vals   = (const float*)d_in[5];
    const float* h0     = (const float*)d_in[6];
    const float* Ws     = (const float*)d_in[7];
    const float* Vs     = (const float*)d_in[8];
    const float* alphas = (const float*)d_in[9];
    const float* Wc     = (const float*)d_in[10];
    const float* bb     = (const float*)d_in[11];
    const float* u      = (const float*)d_in[12];
    float* out = (float*)d_out;

    char* p = (char*)d_ws;
    float*    hB    = (float*)p;    p += (size_t)N_NODES * DOUT * 4;   // 25.6 MB
    float*    aggc  = (float*)p;    p += (size_t)N_NODES * DOUT * 4;   // 25.6 MB
    unsigned* eSrc  = (unsigned*)p; p += (size_t)TE * 4;               // 6 MB
    float*    eVal  = (float*)p;    p += (size_t)TE * 4;               // 6 MB
    int*      counts= (int*)p;      p += 200064;
    int*      offs  = (int*)p;      p += 200064;                        // N+1 ints
    int*      bsums = (int*)p;      p += 1024;
    float*    blockpart = (float*)p; p += LOSS_BLOCKS * 2 * 4;

    const int NB = (N_NODES + 255) / 256;  // 196

    // CSR build (reused for both hops; per-hop alpha applied at read time)
    hipMemsetAsync(counts, 0, (size_t)N_NODES * 4, stream);
    k_hist<<<(TE + 255) / 256, 256, 0, stream>>>(dst, counts, TE);
    k_scan1<<<NB, 256, 0, stream>>>(counts, offs, bsums, N_NODES);
    k_scan2<<<1, 256, 0, stream>>>(bsums, NB);
    k_scan3<<<NB, 256, 0, stream>>>(offs, bsums, N_NODES);
    hipMemsetAsync(counts, 0, (size_t)N_NODES * 4, stream);
    k_scatter<<<(TE + 255) / 256, 256, 0, stream>>>(src, dst, vals, offs, counts, eSrc, eVal, TE);

    const int GBLK = (N_NODES + 63) / 64;  // 782
    for (int hop = 0; hop < NHOP; ++hop) {
        const float* hcur = hop ? (const float*)hB : h0;
        k_agg<<<N_NODES, 128, 0, stream>>>(hcur, eSrc, eVal, offs, alphas + hop * NDEV, aggc);
        k_gemm<<<GBLK, 256, 0, stream>>>(x, Ws + (size_t)hop * DIN * DOUT, hB, nullptr,
                                         N_NODES, DIN, 0);
        k_gemm<<<GBLK, 256, 0, stream>>>(aggc, Vs + (size_t)hop * DOUT * DOUT, hB, hB,
                                         N_NODES, DOUT, 1);
    }

    k_loss<<<LOSS_BLOCKS, 256, 0, stream>>>(hB, label, idx, u, Wc, bb, blockpart, NMASK);
    k_final<<<1, 256, 0, stream>>>(blockpart, out, LOSS_BLOCKS);
}

// Round 3
// 522.078 us; speedup vs baseline: 1.8036x; 1.4193x over previous
//
#include <hip/hip_runtime.h>
#include <hip/hip_bf16.h>

#define N_NODES 50000
#define DIN     256
#define DOUT    128
#define NCLS    2
#define NHOP    2
#define NDEV    3
#define EDG     500000
#define TE      (NDEV*EDG)
#define NMASK   10000
#define LOSS_BLOCKS 100

__device__ __forceinline__ float softplusf(float a) {
    return fmaxf(a, 0.f) + log1pf(expf(-fabsf(a)));
}

// ---------------- CSR build ----------------

__global__ void k_hist(const int* __restrict__ dst, int* __restrict__ counts, int total) {
    int i = blockIdx.x * blockDim.x + threadIdx.x;
    if (i < total) atomicAdd(&counts[dst[i]], 1);
}

__global__ void k_scan1(const int* __restrict__ counts, int* __restrict__ offs,
                        int* __restrict__ bsums, int n) {
    __shared__ int s[256];
    int tid = threadIdx.x;
    int gid = blockIdx.x * 256 + tid;
    int v = (gid < n) ? counts[gid] : 0;
    s[tid] = v; __syncthreads();
    for (int o = 1; o < 256; o <<= 1) {
        int t = (tid >= o) ? s[tid - o] : 0;
        __syncthreads();
        s[tid] += t;
        __syncthreads();
    }
    if (gid < n) offs[gid + 1] = s[tid];
    if (tid == 255) bsums[blockIdx.x] = s[255];
}

__global__ void k_scan2(int* __restrict__ bsums, int nb) {
    __shared__ int s[256];
    int tid = threadIdx.x;
    int v = (tid < nb) ? bsums[tid] : 0;
    s[tid] = v; __syncthreads();
    for (int o = 1; o < 256; o <<= 1) {
        int t = (tid >= o) ? s[tid - o] : 0;
        __syncthreads();
        s[tid] += t;
        __syncthreads();
    }
    if (tid < nb) bsums[tid] = s[tid];  // inclusive
}

__global__ void k_scan3(int* __restrict__ offs, const int* __restrict__ bsums, int n) {
    int gid = blockIdx.x * 256 + threadIdx.x;
    if (gid == 0) offs[0] = 0;
    if (gid < n && blockIdx.x > 0) offs[gid + 1] += bsums[blockIdx.x - 1];
}

// pack edges: e.x = src | (dev<<16), e.y = bits(val)
__global__ void k_scatter(const int* __restrict__ src, const int* __restrict__ dst,
                          const float* __restrict__ vals, const int* __restrict__ offs,
                          int* __restrict__ cur, uint2* __restrict__ ed, int total) {
    int i = blockIdx.x * blockDim.x + threadIdx.x;
    if (i >= total) return;
    int d = i / EDG;
    int n = dst[i];
    int pos = offs[n] + atomicAdd(&cur[n], 1);
    ed[pos] = make_uint2(((unsigned)src[i]) | ((unsigned)d << 16), __float_as_uint(vals[i]));
}

// fp32 -> bf16 row copy (for initial h0)
__global__ void k_cvt(const float* __restrict__ in, __hip_bfloat16* __restrict__ out, int n2) {
    int i = blockIdx.x * blockDim.x + threadIdx.x;  // one float2 -> bf16x2 per thread
    if (i >= n2) return;
    float2 f = ((const float2*)in)[i];
    __hip_bfloat162 b;
    b.x = __float2bfloat16(f.x);
    b.y = __float2bfloat16(f.y);
    ((__hip_bfloat162*)out)[i] = b;
}

// ---------------- sparse aggregation: one wave per node, bf16 gather ----------------
__global__ __launch_bounds__(256) void k_agg(const __hip_bfloat16* __restrict__ hb,
                                             const uint2* __restrict__ ed,
                                             const int* __restrict__ offs,
                                             const float* __restrict__ alpha_hop,
                                             float* __restrict__ aggc) {
    int wid = threadIdx.x >> 6;
    int lane = threadIdx.x & 63;
    int n = blockIdx.x * 4 + wid;
    if (n >= N_NODES) return;
    float a0 = alpha_hop[0], a1 = alpha_hop[1], a2 = alpha_hop[2];
    int beg = offs[n], end = offs[n + 1];
    int col = lane * 2;
    float acc0 = 0.f, acc1 = 0.f, bcc0 = 0.f, bcc1 = 0.f;
    int e = beg;
    for (; e + 4 <= end; e += 4) {
        uint2 m0 = ed[e], m1 = ed[e + 1], m2 = ed[e + 2], m3 = ed[e + 3];
        __hip_bfloat162 g0 = *(const __hip_bfloat162*)(hb + (size_t)(m0.x & 0xFFFFu) * DOUT + col);
        __hip_bfloat162 g1 = *(const __hip_bfloat162*)(hb + (size_t)(m1.x & 0xFFFFu) * DOUT + col);
        __hip_bfloat162 g2 = *(const __hip_bfloat162*)(hb + (size_t)(m2.x & 0xFFFFu) * DOUT + col);
        __hip_bfloat162 g3 = *(const __hip_bfloat162*)(hb + (size_t)(m3.x & 0xFFFFu) * DOUT + col);
        int d0 = m0.x >> 16, d1 = m1.x >> 16, d2 = m2.x >> 16, d3 = m3.x >> 16;
        float w0 = __uint_as_float(m0.y) * (d0 == 0 ? a0 : (d0 == 1 ? a1 : a2));
        float w1 = __uint_as_float(m1.y) * (d1 == 0 ? a0 : (d1 == 1 ? a1 : a2));
        float w2 = __uint_as_float(m2.y) * (d2 == 0 ? a0 : (d2 == 1 ? a1 : a2));
        float w3 = __uint_as_float(m3.y) * (d3 == 0 ? a0 : (d3 == 1 ? a1 : a2));
        float2 f0 = __bfloat1622float2(g0);
        float2 f1 = __bfloat1622float2(g1);
        float2 f2 = __bfloat1622float2(g2);
        float2 f3 = __bfloat1622float2(g3);
        acc0 += w0 * f0.x; acc1 += w0 * f0.y;
        bcc0 += w1 * f1.x; bcc1 += w1 * f1.y;
        acc0 += w2 * f2.x; acc1 += w2 * f2.y;
        bcc0 += w3 * f3.x; bcc1 += w3 * f3.y;
    }
    for (; e < end; ++e) {
        uint2 m = ed[e];
        __hip_bfloat162 g = *(const __hip_bfloat162*)(hb + (size_t)(m.x & 0xFFFFu) * DOUT + col);
        int d = m.x >> 16;
        float w = __uint_as_float(m.y) * (d == 0 ? a0 : (d == 1 ? a1 : a2));
        float2 f = __bfloat1622float2(g);
        acc0 += w * f.x; acc1 += w * f.y;
    }
    *(float2*)(aggc + (size_t)n * DOUT + col) = make_float2(acc0 + bcc0, acc1 + bcc1);
}

// ---------------- fp32 tiled GEMM (+addin, sigmoid, optional bf16 copy) --------------
__global__ __launch_bounds__(256) void k_gemm(const float* __restrict__ A,
                                              const float* __restrict__ B,
                                              float* __restrict__ C,
                                              const float* __restrict__ addin,
                                              __hip_bfloat16* __restrict__ Cb,
                                              int M, int K, int sig) {
    __shared__ float As[32][68];
    __shared__ float Bs[32][128];
    int tid = threadIdx.x;
    int tx = tid & 31;
    int ty = tid >> 5;
    int row0 = blockIdx.x * 64;

    float acc[8][4];
#pragma unroll
    for (int r = 0; r < 8; ++r)
#pragma unroll
        for (int c = 0; c < 4; ++c) acc[r][c] = 0.f;

    int lr = tid >> 2;
    int lk = (tid & 3) * 8;

    for (int k0 = 0; k0 < K; k0 += 32) {
        float4 a0v = make_float4(0, 0, 0, 0), a1v = make_float4(0, 0, 0, 0);
        int arow = row0 + lr;
        if (arow < M) {
            const float4* ap = (const float4*)(A + (size_t)arow * K + k0 + lk);
            a0v = ap[0];
            a1v = ap[1];
        }
        {
            float av[8] = {a0v.x, a0v.y, a0v.z, a0v.w, a1v.x, a1v.y, a1v.z, a1v.w};
#pragma unroll
            for (int j = 0; j < 8; ++j) As[lk + j][lr] = av[j];
        }
#pragma unroll
        for (int j = 0; j < 4; ++j) {
            int fidx = tid + j * 256;
            int kk = fidx >> 5;
            int c4 = fidx & 31;
            float4 g = ((const float4*)B)[(size_t)(k0 + kk) * 32 + c4];
            *(float4*)&Bs[kk][c4 * 4] = g;
        }
        __syncthreads();

#pragma unroll
        for (int kk = 0; kk < 32; ++kk) {
            float4 bA = *(const float4*)&Bs[kk][tx * 4];
            float4 aA = *(const float4*)&As[kk][ty * 8];
            float4 aB = *(const float4*)&As[kk][ty * 8 + 4];
            float ar[8] = {aA.x, aA.y, aA.z, aA.w, aB.x, aB.y, aB.z, aB.w};
            float bc[4] = {bA.x, bA.y, bA.z, bA.w};
#pragma unroll
            for (int r = 0; r < 8; ++r)
#pragma unroll
                for (int c = 0; c < 4; ++c) acc[r][c] += ar[r] * bc[c];
        }
        __syncthreads();
    }

#pragma unroll
    for (int r = 0; r < 8; ++r) {
        int row = row0 + ty * 8 + r;
        if (row < M) {
            float4 v = make_float4(acc[r][0], acc[r][1], acc[r][2], acc[r][3]);
            size_t o = (size_t)row * DOUT + tx * 4;
            if (addin) {
                float4 ad = *(const float4*)(addin + o);
                v.x += ad.x; v.y += ad.y; v.z += ad.z; v.w += ad.w;
            }
            if (sig) {
                v.x = 1.f / (1.f + expf(-v.x));
                v.y = 1.f / (1.f + expf(-v.y));
                v.z = 1.f / (1.f + expf(-v.z));
                v.w = 1.f / (1.f + expf(-v.w));
            }
            *(float4*)(C + o) = v;
            if (Cb) {
                union { __hip_bfloat16 h[4]; ushort4 u; } pk;
                pk.h[0] = __float2bfloat16(v.x);
                pk.h[1] = __float2bfloat16(v.y);
                pk.h[2] = __float2bfloat16(v.z);
                pk.h[3] = __float2bfloat16(v.w);
                *(ushort4*)(Cb + o) = pk.u;
            }
        }
    }
}

// ---------------- masked loss + accuracy (no global atomics) ----------------
__global__ __launch_bounds__(256) void k_loss(const float* __restrict__ h,
                                              const float* __restrict__ label,
                                              const int* __restrict__ idx,
                                              const float* __restrict__ u,
                                              const float* __restrict__ Wc,
                                              const float* __restrict__ bb,
                                              float* __restrict__ blockpart, int Mtot) {
    __shared__ float sl[4], sc[4];
    int wid = threadIdx.x >> 6;
    int lane = threadIdx.x & 63;
    int gw = blockIdx.x * 4 + wid;
    int nw = gridDim.x * 4;
    float uv0 = u[lane], uv1 = u[64 + lane];
    float wc00 = Wc[lane * 2 + 0], wc01 = Wc[lane * 2 + 1];
    float wc10 = Wc[(lane + 64) * 2 + 0], wc11 = Wc[(lane + 64) * 2 + 1];
    float b0 = bb[0], b1 = bb[1];
    float lsum = 0.f, csum = 0.f;
    for (int w = gw; w < Mtot; w += nw) {
        int node = idx[w];
        float v0 = h[(size_t)node * DOUT + lane];
        float v1 = h[(size_t)node * DOUT + 64 + lane];
        float ps = v0 * uv0 + v1 * uv1;
        float p0 = v0 * wc00 + v1 * wc10;
        float p1 = v0 * wc01 + v1 * wc11;
#pragma unroll
        for (int o = 32; o > 0; o >>= 1) {
            ps += __shfl_xor(ps, o, 64);
            p0 += __shfl_xor(p0, o, 64);
            p1 += __shfl_xor(p1, o, 64);
        }
        if (lane == 0) {
            float y0 = label[(size_t)node * NCLS + 0];
            float y1 = label[(size_t)node * NCLS + 1];
            lsum += softplusf(-(y0 * ps)) + softplusf(-(y1 * ps));
            float l0 = p0 + b0, l1 = p1 + b1;
            int pred = (l1 > l0) ? 1 : 0;
            int truth = (y1 > y0) ? 1 : 0;
            csum += (pred == truth) ? 1.f : 0.f;
        }
    }
    if (lane == 0) { sl[wid] = lsum; sc[wid] = csum; }
    __syncthreads();
    if (threadIdx.x == 0) {
        blockpart[blockIdx.x * 2 + 0] = sl[0] + sl[1] + sl[2] + sl[3];
        blockpart[blockIdx.x * 2 + 1] = sc[0] + sc[1] + sc[2] + sc[3];
    }
}

__global__ __launch_bounds__(256) void k_final(const float* __restrict__ bp,
                                               float* __restrict__ out, int nb) {
    __shared__ float sl[256], sc[256];
    int t = threadIdx.x;
    float l = 0.f, c = 0.f;
    for (int i = t; i < nb; i += 256) { l += bp[i * 2]; c += bp[i * 2 + 1]; }
    sl[t] = l; sc[t] = c;
    __syncthreads();
    for (int o = 128; o > 0; o >>= 1) {
        if (t < o) { sl[t] += sl[t + o]; sc[t] += sc[t + o]; }
        __syncthreads();
    }
    if (t == 0) { out[0] = sl[0]; out[1] = sc[0] * (1.0f / NMASK); }
}

// ---------------- launch ----------------
extern "C" void kernel_launch(void* const* d_in, const int* in_sizes, int n_in,
                              void* d_out, int out_size, void* d_ws, size_t ws_size,
                              hipStream_t stream) {
    const float* x      = (const float*)d_in[0];
    const float* label  = (const float*)d_in[1];
    const int*   idx    = (const int*)d_in[2];
    const int*   src    = (const int*)d_in[3];
    const int*   dst    = (const int*)d_in[4];
    const float* vals   = (const float*)d_in[5];
    const float* h0     = (const float*)d_in[6];
    const float* Ws     = (const float*)d_in[7];
    const float* Vs     = (const float*)d_in[8];
    const float* alphas = (const float*)d_in[9];
    const float* Wc     = (const float*)d_in[10];
    const float* bb     = (const float*)d_in[11];
    const float* u      = (const float*)d_in[12];
    float* out = (float*)d_out;

    char* p = (char*)d_ws;
    float*          hB   = (float*)p;          p += (size_t)N_NODES * DOUT * 4;  // 25.6 MB
    float*          aggc = (float*)p;          p += (size_t)N_NODES * DOUT * 4;  // 25.6 MB
    __hip_bfloat16* hbf  = (__hip_bfloat16*)p; p += (size_t)N_NODES * DOUT * 2;  // 12.8 MB
    uint2*          ed   = (uint2*)p;          p += (size_t)TE * 8;              // 12 MB
    int*            counts = (int*)p;          p += 200064;
    int*            offs   = (int*)p;          p += 200064;
    int*            bsums  = (int*)p;          p += 1024;
    float*          blockpart = (float*)p;     p += LOSS_BLOCKS * 2 * 4;

    const int NB = (N_NODES + 255) / 256;  // 196

    // CSR build (reused for both hops)
    hipMemsetAsync(counts, 0, (size_t)N_NODES * 4, stream);
    k_hist<<<(TE + 255) / 256, 256, 0, stream>>>(dst, counts, TE);
    k_scan1<<<NB, 256, 0, stream>>>(counts, offs, bsums, N_NODES);
    k_scan2<<<1, 256, 0, stream>>>(bsums, NB);
    k_scan3<<<NB, 256, 0, stream>>>(offs, bsums, N_NODES);
    hipMemsetAsync(counts, 0, (size_t)N_NODES * 4, stream);
    k_scatter<<<(TE + 255) / 256, 256, 0, stream>>>(src, dst, vals, offs, counts, ed, TE);

    // bf16 copy of h0 for the first-hop gather
    k_cvt<<<(N_NODES * DOUT / 2 + 255) / 256, 256, 0, stream>>>(h0, hbf, N_NODES * DOUT / 2);

    const int GBLK = (N_NODES + 63) / 64;  // 782
    for (int hop = 0; hop < NHOP; ++hop) {
        k_agg<<<(N_NODES + 3) / 4, 256, 0, stream>>>(hbf, ed, offs, alphas + hop * NDEV, aggc);
        k_gemm<<<GBLK, 256, 0, stream>>>(x, Ws + (size_t)hop * DIN * DOUT, hB, nullptr,
                                         nullptr, N_NODES, DIN, 0);
        // hB = sigmoid(hB + aggc @ Vs[hop]); also emit bf16 copy for next hop's gather
        k_gemm<<<GBLK, 256, 0, stream>>>(aggc, Vs + (size_t)hop * DOUT * DOUT, hB, hB,
                                         hbf, N_NODES, DOUT, 1);
    }

    k_loss<<<LOSS_BLOCKS, 256, 0, stream>>>(hB, label, idx, u, Wc, bb, blockpart, NMASK);
    k_final<<<1, 256, 0, stream>>>(blockpart, out, LOSS_BLOCKS);
}

// Round 4
// 401.891 us; speedup vs baseline: 2.3430x; 1.2991x over previous
//
#include <hip/hip_runtime.h>
#include <hip/hip_bf16.h>

#define N_NODES 50000
#define DIN     256
#define DOUT    128
#define NCLS    2
#define NHOP    2
#define NDEV    3
#define EDG     500000
#define TE      (NDEV*EDG)
#define NMASK   10000
#define LOSS_BLOCKS 100

#define BUCK    64
#define NBUCK   782                  // ceil(50000/64)
#define CH      8192                 // edges per binning block
#define NBLKA   184                  // ceil(TE/CH)
#define BHN     (NBUCK*NBLKA)        // 143888
#define SCT     512
#define SCANBLKS ((BHN + SCT - 1) / SCT)   // 282

__device__ __forceinline__ float softplusf(float a) {
    return fmaxf(a, 0.f) + log1pf(expf(-fabsf(a)));
}

// ---------------- bucket-binned CSR build (write-amp ~1x) ----------------

__global__ __launch_bounds__(256) void k_bhist(const int* __restrict__ dst,
                                               int* __restrict__ bh) {
    __shared__ int hist[NBUCK];
    int blk = blockIdx.x, tid = threadIdx.x;
    for (int i = tid; i < NBUCK; i += 256) hist[i] = 0;
    __syncthreads();
    int base = blk * CH;
    int lim = min(base + CH, TE);
    for (int i = base + tid; i < lim; i += 256) atomicAdd(&hist[dst[i] >> 6], 1);
    __syncthreads();
    for (int i = tid; i < NBUCK; i += 256) bh[(size_t)i * NBLKA + blk] = hist[i];
}

__global__ __launch_bounds__(SCT) void k_scanA(const int* __restrict__ in,
                                               int* __restrict__ out,
                                               int* __restrict__ bsums, int n) {
    __shared__ int s[SCT];
    int tid = threadIdx.x, gid = blockIdx.x * SCT + tid;
    int v = (gid < n) ? in[gid] : 0;
    s[tid] = v; __syncthreads();
    for (int o = 1; o < SCT; o <<= 1) {
        int t = (tid >= o) ? s[tid - o] : 0;
        __syncthreads();
        s[tid] += t;
        __syncthreads();
    }
    if (gid < n) out[gid] = s[tid] - v;          // exclusive
    if (tid == SCT - 1) bsums[blockIdx.x] = s[SCT - 1];
}

__global__ __launch_bounds__(SCT) void k_scanB(int* __restrict__ bsums, int nb) {
    __shared__ int s[SCT];
    int tid = threadIdx.x;
    int v = (tid < nb) ? bsums[tid] : 0;
    s[tid] = v; __syncthreads();
    for (int o = 1; o < SCT; o <<= 1) {
        int t = (tid >= o) ? s[tid - o] : 0;
        __syncthreads();
        s[tid] += t;
        __syncthreads();
    }
    if (tid < nb) bsums[tid] = s[tid] - v;       // exclusive
}

__global__ __launch_bounds__(SCT) void k_scanC(int* __restrict__ out,
                                               const int* __restrict__ bsums, int n) {
    int gid = blockIdx.x * SCT + threadIdx.x;
    if (gid < n) out[gid] += bsums[blockIdx.x];
}

// bin edges into bucket-grouped array; pack src(16) | dev(2)<<16 | dstlocal(6)<<18
__global__ __launch_bounds__(256) void k_bbin(const int* __restrict__ src,
                                              const int* __restrict__ dst,
                                              const float* __restrict__ vals,
                                              const int* __restrict__ sc,
                                              uint2* __restrict__ ebkt) {
    __shared__ int cur[NBUCK];
    int blk = blockIdx.x, tid = threadIdx.x;
    for (int i = tid; i < NBUCK; i += 256) cur[i] = sc[(size_t)i * NBLKA + blk];
    __syncthreads();
    int base = blk * CH;
    int lim = min(base + CH, TE);
    for (int i = base + tid; i < lim; i += 256) {
        int d = i / EDG;
        int n = dst[i];
        int bu = n >> 6;
        int pos = atomicAdd(&cur[bu], 1);
        ebkt[pos] = make_uint2((unsigned)src[i] | ((unsigned)d << 16) |
                               ((unsigned)(n & 63) << 18),
                               __float_as_uint(vals[i]));
    }
}

// per-bucket counting sort by node; emits final edge array + per-node offsets
__global__ __launch_bounds__(256) void k_bsort(const uint2* __restrict__ ebkt,
                                               const int* __restrict__ sc,
                                               uint2* __restrict__ ed,
                                               int* __restrict__ offs) {
    __shared__ int cnt[BUCK], start[BUCK + 1], cur[BUCK];
    int b = blockIdx.x, tid = threadIdx.x;
    int beg = sc[(size_t)b * NBLKA];
    int end = (b + 1 < NBUCK) ? sc[(size_t)(b + 1) * NBLKA] : TE;
    if (tid < BUCK) { cnt[tid] = 0; cur[tid] = 0; }
    __syncthreads();
    for (int e = beg + tid; e < end; e += 256)
        atomicAdd(&cnt[(ebkt[e].x >> 18) & 63], 1);
    __syncthreads();
    if (tid == 0) {
        int acc = 0;
        for (int i = 0; i < BUCK; ++i) { start[i] = acc; acc += cnt[i]; }
        start[BUCK] = acc;
    }
    __syncthreads();
    if (tid < BUCK) {
        int n = b * BUCK + tid;
        if (n < N_NODES) offs[n] = beg + start[tid];
    }
    if (b == 0 && tid == 255) offs[N_NODES] = TE;
    for (int e = beg + tid; e < end; e += 256) {
        uint2 v = ebkt[e];
        int dl = (v.x >> 18) & 63;
        int pos = beg + start[dl] + atomicAdd(&cur[dl], 1);
        ed[pos] = make_uint2(v.x & 0x3FFFFu, v.y);
    }
}

// fp32 -> bf16 row copy (for initial h0)
__global__ void k_cvt(const float* __restrict__ in, __hip_bfloat16* __restrict__ out, int n2) {
    int i = blockIdx.x * blockDim.x + threadIdx.x;
    if (i >= n2) return;
    float2 f = ((const float2*)in)[i];
    __hip_bfloat162 b;
    b.x = __float2bfloat16(f.x);
    b.y = __float2bfloat16(f.y);
    ((__hip_bfloat162*)out)[i] = b;
}

// ---------------- sparse aggregation: one wave per node, bf16 gather ----------------
__global__ __launch_bounds__(256) void k_agg(const __hip_bfloat16* __restrict__ hb,
                                             const uint2* __restrict__ ed,
                                             const int* __restrict__ offs,
                                             const float* __restrict__ alpha_hop,
                                             float* __restrict__ aggc) {
    int wid = threadIdx.x >> 6;
    int lane = threadIdx.x & 63;
    int n = blockIdx.x * 4 + wid;
    if (n >= N_NODES) return;
    float a0 = alpha_hop[0], a1 = alpha_hop[1], a2 = alpha_hop[2];
    int beg = offs[n], end = offs[n + 1];
    int col = lane * 2;
    float acc0 = 0.f, acc1 = 0.f, bcc0 = 0.f, bcc1 = 0.f;
    int e = beg;
    for (; e + 4 <= end; e += 4) {
        uint2 m0 = ed[e], m1 = ed[e + 1], m2 = ed[e + 2], m3 = ed[e + 3];
        __hip_bfloat162 g0 = *(const __hip_bfloat162*)(hb + (size_t)(m0.x & 0xFFFFu) * DOUT + col);
        __hip_bfloat162 g1 = *(const __hip_bfloat162*)(hb + (size_t)(m1.x & 0xFFFFu) * DOUT + col);
        __hip_bfloat162 g2 = *(const __hip_bfloat162*)(hb + (size_t)(m2.x & 0xFFFFu) * DOUT + col);
        __hip_bfloat162 g3 = *(const __hip_bfloat162*)(hb + (size_t)(m3.x & 0xFFFFu) * DOUT + col);
        int d0 = m0.x >> 16, d1 = m1.x >> 16, d2 = m2.x >> 16, d3 = m3.x >> 16;
        float w0 = __uint_as_float(m0.y) * (d0 == 0 ? a0 : (d0 == 1 ? a1 : a2));
        float w1 = __uint_as_float(m1.y) * (d1 == 0 ? a0 : (d1 == 1 ? a1 : a2));
        float w2 = __uint_as_float(m2.y) * (d2 == 0 ? a0 : (d2 == 1 ? a1 : a2));
        float w3 = __uint_as_float(m3.y) * (d3 == 0 ? a0 : (d3 == 1 ? a1 : a2));
        float2 f0 = __bfloat1622float2(g0);
        float2 f1 = __bfloat1622float2(g1);
        float2 f2 = __bfloat1622float2(g2);
        float2 f3 = __bfloat1622float2(g3);
        acc0 += w0 * f0.x; acc1 += w0 * f0.y;
        bcc0 += w1 * f1.x; bcc1 += w1 * f1.y;
        acc0 += w2 * f2.x; acc1 += w2 * f2.y;
        bcc0 += w3 * f3.x; bcc1 += w3 * f3.y;
    }
    for (; e < end; ++e) {
        uint2 m = ed[e];
        __hip_bfloat162 g = *(const __hip_bfloat162*)(hb + (size_t)(m.x & 0xFFFFu) * DOUT + col);
        int d = m.x >> 16;
        float w = __uint_as_float(m.y) * (d == 0 ? a0 : (d == 1 ? a1 : a2));
        float2 f = __bfloat1622float2(g);
        acc0 += w * f.x; acc1 += w * f.y;
    }
    *(float2*)(aggc + (size_t)n * DOUT + col) = make_float2(acc0 + bcc0, acc1 + bcc1);
}

// ---------------- fp32 tiled GEMM (+addin, sigmoid, optional bf16 copy) --------------
__global__ __launch_bounds__(256) void k_gemm(const float* __restrict__ A,
                                              const float* __restrict__ B,
                                              float* __restrict__ C,
                                              const float* __restrict__ addin,
                                              __hip_bfloat16* __restrict__ Cb,
                                              int M, int K, int sig) {
    __shared__ float As[32][68];
    __shared__ float Bs[32][128];
    int tid = threadIdx.x;
    int tx = tid & 31;
    int ty = tid >> 5;
    int row0 = blockIdx.x * 64;

    float acc[8][4];
#pragma unroll
    for (int r = 0; r < 8; ++r)
#pragma unroll
        for (int c = 0; c < 4; ++c) acc[r][c] = 0.f;

    int lr = tid >> 2;
    int lk = (tid & 3) * 8;

    for (int k0 = 0; k0 < K; k0 += 32) {
        float4 a0v = make_float4(0, 0, 0, 0), a1v = make_float4(0, 0, 0, 0);
        int arow = row0 + lr;
        if (arow < M) {
            const float4* ap = (const float4*)(A + (size_t)arow * K + k0 + lk);
            a0v = ap[0];
            a1v = ap[1];
        }
        {
            float av[8] = {a0v.x, a0v.y, a0v.z, a0v.w, a1v.x, a1v.y, a1v.z, a1v.w};
#pragma unroll
            for (int j = 0; j < 8; ++j) As[lk + j][lr] = av[j];
        }
#pragma unroll
        for (int j = 0; j < 4; ++j) {
            int fidx = tid + j * 256;
            int kk = fidx >> 5;
            int c4 = fidx & 31;
            float4 g = ((const float4*)B)[(size_t)(k0 + kk) * 32 + c4];
            *(float4*)&Bs[kk][c4 * 4] = g;
        }
        __syncthreads();

#pragma unroll
        for (int kk = 0; kk < 32; ++kk) {
            float4 bA = *(const float4*)&Bs[kk][tx * 4];
            float4 aA = *(const float4*)&As[kk][ty * 8];
            float4 aB = *(const float4*)&As[kk][ty * 8 + 4];
            float ar[8] = {aA.x, aA.y, aA.z, aA.w, aB.x, aB.y, aB.z, aB.w};
            float bc[4] = {bA.x, bA.y, bA.z, bA.w};
#pragma unroll
            for (int r = 0; r < 8; ++r)
#pragma unroll
                for (int c = 0; c < 4; ++c) acc[r][c] += ar[r] * bc[c];
        }
        __syncthreads();
    }

#pragma unroll
    for (int r = 0; r < 8; ++r) {
        int row = row0 + ty * 8 + r;
        if (row < M) {
            float4 v = make_float4(acc[r][0], acc[r][1], acc[r][2], acc[r][3]);
            size_t o = (size_t)row * DOUT + tx * 4;
            if (addin) {
                float4 ad = *(const float4*)(addin + o);
                v.x += ad.x; v.y += ad.y; v.z += ad.z; v.w += ad.w;
            }
            if (sig) {
                v.x = 1.f / (1.f + expf(-v.x));
                v.y = 1.f / (1.f + expf(-v.y));
                v.z = 1.f / (1.f + expf(-v.z));
                v.w = 1.f / (1.f + expf(-v.w));
            }
            *(float4*)(C + o) = v;
            if (Cb) {
                union { __hip_bfloat16 h[4]; ushort4 u; } pk;
                pk.h[0] = __float2bfloat16(v.x);
                pk.h[1] = __float2bfloat16(v.y);
                pk.h[2] = __float2bfloat16(v.z);
                pk.h[3] = __float2bfloat16(v.w);
                *(ushort4*)(Cb + o) = pk.u;
            }
        }
    }
}

// ---------------- masked loss + accuracy (no global atomics) ----------------
__global__ __launch_bounds__(256) void k_loss(const float* __restrict__ h,
                                              const float* __restrict__ label,
                                              const int* __restrict__ idx,
                                              const float* __restrict__ u,
                                              const float* __restrict__ Wc,
                                              const float* __restrict__ bb,
                                              float* __restrict__ blockpart, int Mtot) {
    __shared__ float sl[4], sc[4];
    int wid = threadIdx.x >> 6;
    int lane = threadIdx.x & 63;
    int gw = blockIdx.x * 4 + wid;
    int nw = gridDim.x * 4;
    float uv0 = u[lane], uv1 = u[64 + lane];
    float wc00 = Wc[lane * 2 + 0], wc01 = Wc[lane * 2 + 1];
    float wc10 = Wc[(lane + 64) * 2 + 0], wc11 = Wc[(lane + 64) * 2 + 1];
    float b0 = bb[0], b1 = bb[1];
    float lsum = 0.f, csum = 0.f;
    for (int w = gw; w < Mtot; w += nw) {
        int node = idx[w];
        float v0 = h[(size_t)node * DOUT + lane];
        float v1 = h[(size_t)node * DOUT + 64 + lane];
        float ps = v0 * uv0 + v1 * uv1;
        float p0 = v0 * wc00 + v1 * wc10;
        float p1 = v0 * wc01 + v1 * wc11;
#pragma unroll
        for (int o = 32; o > 0; o >>= 1) {
            ps += __shfl_xor(ps, o, 64);
            p0 += __shfl_xor(p0, o, 64);
            p1 += __shfl_xor(p1, o, 64);
        }
        if (lane == 0) {
            float y0 = label[(size_t)node * NCLS + 0];
            float y1 = label[(size_t)node * NCLS + 1];
            lsum += softplusf(-(y0 * ps)) + softplusf(-(y1 * ps));
            float l0 = p0 + b0, l1 = p1 + b1;
            int pred = (l1 > l0) ? 1 : 0;
            int truth = (y1 > y0) ? 1 : 0;
            csum += (pred == truth) ? 1.f : 0.f;
        }
    }
    if (lane == 0) { sl[wid] = lsum; sc[wid] = csum; }
    __syncthreads();
    if (threadIdx.x == 0) {
        blockpart[blockIdx.x * 2 + 0] = sl[0] + sl[1] + sl[2] + sl[3];
        blockpart[blockIdx.x * 2 + 1] = sc[0] + sc[1] + sc[2] + sc[3];
    }
}

__global__ __launch_bounds__(256) void k_final(const float* __restrict__ bp,
                                               float* __restrict__ out, int nb) {
    __shared__ float sl[256], sc[256];
    int t = threadIdx.x;
    float l = 0.f, c = 0.f;
    for (int i = t; i < nb; i += 256) { l += bp[i * 2]; c += bp[i * 2 + 1]; }
    sl[t] = l; sc[t] = c;
    __syncthreads();
    for (int o = 128; o > 0; o >>= 1) {
        if (t < o) { sl[t] += sl[t + o]; sc[t] += sc[t + o]; }
        __syncthreads();
    }
    if (t == 0) { out[0] = sl[0]; out[1] = sc[0] * (1.0f / NMASK); }
}

// ---------------- launch ----------------
extern "C" void kernel_launch(void* const* d_in, const int* in_sizes, int n_in,
                              void* d_out, int out_size, void* d_ws, size_t ws_size,
                              hipStream_t stream) {
    const float* x      = (const float*)d_in[0];
    const float* label  = (const float*)d_in[1];
    const int*   idx    = (const int*)d_in[2];
    const int*   src    = (const int*)d_in[3];
    const int*   dst    = (const int*)d_in[4];
    const float* vals   = (const float*)d_in[5];
    const float* h0     = (const float*)d_in[6];
    const float* Ws     = (const float*)d_in[7];
    const float* Vs     = (const float*)d_in[8];
    const float* alphas = (const float*)d_in[9];
    const float* Wc     = (const float*)d_in[10];
    const float* bb     = (const float*)d_in[11];
    const float* u      = (const float*)d_in[12];
    float* out = (float*)d_out;

    char* p = (char*)d_ws;
    float*          hB   = (float*)p;          p += (size_t)N_NODES * DOUT * 4;  // 25.6 MB
    float*          aggc = (float*)p;          p += (size_t)N_NODES * DOUT * 4;  // 25.6 MB
    __hip_bfloat16* hbf  = (__hip_bfloat16*)p; p += (size_t)N_NODES * DOUT * 2;  // 12.8 MB
    uint2*          ed   = (uint2*)p;          p += (size_t)TE * 8;              // 12 MB
    int*            offs = (int*)p;            p += 200064;                      // N+1 ints
    int*            bh   = (int*)p;            p += (size_t)BHN * 4;             // 576 KB
    int*            sc   = (int*)p;            p += (size_t)BHN * 4;             // 576 KB
    int*            bsums= (int*)p;            p += SCT * 4;
    float*          blockpart = (float*)p;     p += LOSS_BLOCKS * 2 * 4;
    // ebkt aliases aggc (dead until k_agg; ebkt dead after k_bsort)
    uint2*          ebkt = (uint2*)aggc;

    // bucket-binned CSR build (reused for both hops)
    k_bhist<<<NBLKA, 256, 0, stream>>>(dst, bh);
    k_scanA<<<SCANBLKS, SCT, 0, stream>>>(bh, sc, bsums, BHN);
    k_scanB<<<1, SCT, 0, stream>>>(bsums, SCANBLKS);
    k_scanC<<<SCANBLKS, SCT, 0, stream>>>(sc, bsums, BHN);
    k_bbin<<<NBLKA, 256, 0, stream>>>(src, dst, vals, sc, ebkt);
    k_bsort<<<NBUCK, 256, 0, stream>>>(ebkt, sc, ed, offs);

    // bf16 copy of h0 for the first-hop gather
    k_cvt<<<(N_NODES * DOUT / 2 + 255) / 256, 256, 0, stream>>>(h0, hbf, N_NODES * DOUT / 2);

    const int GBLK = (N_NODES + 63) / 64;  // 782
    for (int hop = 0; hop < NHOP; ++hop) {
        k_agg<<<(N_NODES + 3) / 4, 256, 0, stream>>>(hbf, ed, offs, alphas + hop * NDEV, aggc);
        k_gemm<<<GBLK, 256, 0, stream>>>(x, Ws + (size_t)hop * DIN * DOUT, hB, nullptr,
                                         nullptr, N_NODES, DIN, 0);
        k_gemm<<<GBLK, 256, 0, stream>>>(aggc, Vs + (size_t)hop * DOUT * DOUT, hB, hB,
                                         hbf, N_NODES, DOUT, 1);
    }

    k_loss<<<LOSS_BLOCKS, 256, 0, stream>>>(hB, label, idx, u, Wc, bb, blockpart, NMASK);
    k_final<<<1, 256, 0, stream>>>(blockpart, out, LOSS_BLOCKS);
}

// Round 5
// 277.958 us; speedup vs baseline: 3.3877x; 1.4459x over previous
//
#include <hip/hip_runtime.h>
#include <hip/hip_bf16.h>

#define N_NODES 50000
#define DIN     256
#define DOUT    128
#define NCLS    2
#define NHOP    2
#define NDEV    3
#define EDG     500000
#define TE      (NDEV*EDG)
#define NMASK   10000
#define LOSS_BLOCKS 100

#define BUCK    64
#define NBUCK   782                  // ceil(50000/64)
#define CH      8192                 // edges per binning block
#define NBLKA   184                  // ceil(TE/CH)
#define BHN     (NBUCK*NBLKA)        // 143888
#define SCT     512
#define SCANBLKS ((BHN + SCT - 1) / SCT)   // 282

typedef __attribute__((ext_vector_type(8))) short bf16x8;   // 8 bf16 = 4 VGPRs
typedef __attribute__((ext_vector_type(4))) float f32x4;

__device__ __forceinline__ float softplusf(float a) {
    return fmaxf(a, 0.f) + log1pf(expf(-fabsf(a)));
}

// ---------------- bucket-binned CSR build (write-amp ~1x) ----------------

__global__ __launch_bounds__(256) void k_bhist(const int* __restrict__ dst,
                                               int* __restrict__ bh) {
    __shared__ int hist[NBUCK];
    int blk = blockIdx.x, tid = threadIdx.x;
    for (int i = tid; i < NBUCK; i += 256) hist[i] = 0;
    __syncthreads();
    int base = blk * CH;
    int lim = min(base + CH, TE);
    for (int i = base + tid; i < lim; i += 256) atomicAdd(&hist[dst[i] >> 6], 1);
    __syncthreads();
    for (int i = tid; i < NBUCK; i += 256) bh[(size_t)i * NBLKA + blk] = hist[i];
}

__global__ __launch_bounds__(SCT) void k_scanA(const int* __restrict__ in,
                                               int* __restrict__ out,
                                               int* __restrict__ bsums, int n) {
    __shared__ int s[SCT];
    int tid = threadIdx.x, gid = blockIdx.x * SCT + tid;
    int v = (gid < n) ? in[gid] : 0;
    s[tid] = v; __syncthreads();
    for (int o = 1; o < SCT; o <<= 1) {
        int t = (tid >= o) ? s[tid - o] : 0;
        __syncthreads();
        s[tid] += t;
        __syncthreads();
    }
    if (gid < n) out[gid] = s[tid] - v;          // exclusive
    if (tid == SCT - 1) bsums[blockIdx.x] = s[SCT - 1];
}

__global__ __launch_bounds__(SCT) void k_scanB(int* __restrict__ bsums, int nb) {
    __shared__ int s[SCT];
    int tid = threadIdx.x;
    int v = (tid < nb) ? bsums[tid] : 0;
    s[tid] = v; __syncthreads();
    for (int o = 1; o < SCT; o <<= 1) {
        int t = (tid >= o) ? s[tid - o] : 0;
        __syncthreads();
        s[tid] += t;
        __syncthreads();
    }
    if (tid < nb) bsums[tid] = s[tid] - v;       // exclusive
}

__global__ __launch_bounds__(SCT) void k_scanC(int* __restrict__ out,
                                               const int* __restrict__ bsums, int n) {
    int gid = blockIdx.x * SCT + threadIdx.x;
    if (gid < n) out[gid] += bsums[blockIdx.x];
}

// bin edges into bucket-grouped array; pack src(16) | dev(2)<<16 | dstlocal(6)<<18
__global__ __launch_bounds__(256) void k_bbin(const int* __restrict__ src,
                                              const int* __restrict__ dst,
                                              const float* __restrict__ vals,
                                              const int* __restrict__ sc,
                                              uint2* __restrict__ ebkt) {
    __shared__ int cur[NBUCK];
    int blk = blockIdx.x, tid = threadIdx.x;
    for (int i = tid; i < NBUCK; i += 256) cur[i] = sc[(size_t)i * NBLKA + blk];
    __syncthreads();
    int base = blk * CH;
    int lim = min(base + CH, TE);
    for (int i = base + tid; i < lim; i += 256) {
        int d = i / EDG;
        int n = dst[i];
        int bu = n >> 6;
        int pos = atomicAdd(&cur[bu], 1);
        ebkt[pos] = make_uint2((unsigned)src[i] | ((unsigned)d << 16) |
                               ((unsigned)(n & 63) << 18),
                               __float_as_uint(vals[i]));
    }
}

// per-bucket counting sort by node; emits final edge array + per-node offsets
__global__ __launch_bounds__(256) void k_bsort(const uint2* __restrict__ ebkt,
                                               const int* __restrict__ sc,
                                               uint2* __restrict__ ed,
                                               int* __restrict__ offs) {
    __shared__ int cnt[BUCK], start[BUCK + 1], cur[BUCK];
    int b = blockIdx.x, tid = threadIdx.x;
    int beg = sc[(size_t)b * NBLKA];
    int end = (b + 1 < NBUCK) ? sc[(size_t)(b + 1) * NBLKA] : TE;
    if (tid < BUCK) { cnt[tid] = 0; cur[tid] = 0; }
    __syncthreads();
    for (int e = beg + tid; e < end; e += 256)
        atomicAdd(&cnt[(ebkt[e].x >> 18) & 63], 1);
    __syncthreads();
    if (tid == 0) {
        int acc = 0;
        for (int i = 0; i < BUCK; ++i) { start[i] = acc; acc += cnt[i]; }
        start[BUCK] = acc;
    }
    __syncthreads();
    if (tid < BUCK) {
        int n = b * BUCK + tid;
        if (n < N_NODES) offs[n] = beg + start[tid];
    }
    if (b == 0 && tid == 255) offs[N_NODES] = TE;
    for (int e = beg + tid; e < end; e += 256) {
        uint2 v = ebkt[e];
        int dl = (v.x >> 18) & 63;
        int pos = beg + start[dl] + atomicAdd(&cur[dl], 1);
        ed[pos] = make_uint2(v.x & 0x3FFFFu, v.y);
    }
}

// fp32 -> bf16 copy (float2 per thread)
__global__ void k_cvt(const float* __restrict__ in, __hip_bfloat16* __restrict__ out, int n2) {
    int i = blockIdx.x * blockDim.x + threadIdx.x;
    if (i >= n2) return;
    float2 f = ((const float2*)in)[i];
    __hip_bfloat162 b;
    b.x = __float2bfloat16(f.x);
    b.y = __float2bfloat16(f.y);
    ((__hip_bfloat162*)out)[i] = b;
}

// weight transpose+convert: WsT[hop][n][k] = bf16(Ws[hop][k][n]); same for Vs
__global__ void k_tw(const float* __restrict__ Ws, const float* __restrict__ Vs,
                     __hip_bfloat16* __restrict__ WsT, __hip_bfloat16* __restrict__ VsT) {
    int i = blockIdx.x * 256 + threadIdx.x;
    if (i < NHOP * DIN * DOUT) {
        int hop = i / (DIN * DOUT);
        int r = i % (DIN * DOUT);
        int k = r >> 7, n = r & 127;
        WsT[(size_t)hop * DOUT * DIN + (size_t)n * DIN + k] = __float2bfloat16(Ws[i]);
    } else {
        int j = i - NHOP * DIN * DOUT;
        if (j < NHOP * DOUT * DOUT) {
            int hop = j / (DOUT * DOUT);
            int r = j % (DOUT * DOUT);
            int k = r >> 7, n = r & 127;
            VsT[(size_t)hop * DOUT * DOUT + (size_t)n * DOUT + k] = __float2bfloat16(Vs[j]);
        }
    }
}

// ---------------- sparse aggregation: one wave per node, bf16 in/out ----------------
__global__ __launch_bounds__(256) void k_agg(const __hip_bfloat16* __restrict__ hb,
                                             const uint2* __restrict__ ed,
                                             const int* __restrict__ offs,
                                             const float* __restrict__ alpha_hop,
                                             __hip_bfloat16* __restrict__ aggcb) {
    int wid = threadIdx.x >> 6;
    int lane = threadIdx.x & 63;
    int n = blockIdx.x * 4 + wid;
    if (n >= N_NODES) return;
    float a0 = alpha_hop[0], a1 = alpha_hop[1], a2 = alpha_hop[2];
    int beg = offs[n], end = offs[n + 1];
    int col = lane * 2;
    float acc0 = 0.f, acc1 = 0.f, bcc0 = 0.f, bcc1 = 0.f;
    int e = beg;
    for (; e + 4 <= end; e += 4) {
        uint2 m0 = ed[e], m1 = ed[e + 1], m2 = ed[e + 2], m3 = ed[e + 3];
        __hip_bfloat162 g0 = *(const __hip_bfloat162*)(hb + (size_t)(m0.x & 0xFFFFu) * DOUT + col);
        __hip_bfloat162 g1 = *(const __hip_bfloat162*)(hb + (size_t)(m1.x & 0xFFFFu) * DOUT + col);
        __hip_bfloat162 g2 = *(const __hip_bfloat162*)(hb + (size_t)(m2.x & 0xFFFFu) * DOUT + col);
        __hip_bfloat162 g3 = *(const __hip_bfloat162*)(hb + (size_t)(m3.x & 0xFFFFu) * DOUT + col);
        int d0 = m0.x >> 16, d1 = m1.x >> 16, d2 = m2.x >> 16, d3 = m3.x >> 16;
        float w0 = __uint_as_float(m0.y) * (d0 == 0 ? a0 : (d0 == 1 ? a1 : a2));
        float w1 = __uint_as_float(m1.y) * (d1 == 0 ? a0 : (d1 == 1 ? a1 : a2));
        float w2 = __uint_as_float(m2.y) * (d2 == 0 ? a0 : (d2 == 1 ? a1 : a2));
        float w3 = __uint_as_float(m3.y) * (d3 == 0 ? a0 : (d3 == 1 ? a1 : a2));
        float2 f0 = __bfloat1622float2(g0);
        float2 f1 = __bfloat1622float2(g1);
        float2 f2 = __bfloat1622float2(g2);
        float2 f3 = __bfloat1622float2(g3);
        acc0 += w0 * f0.x; acc1 += w0 * f0.y;
        bcc0 += w1 * f1.x; bcc1 += w1 * f1.y;
        acc0 += w2 * f2.x; acc1 += w2 * f2.y;
        bcc0 += w3 * f3.x; bcc1 += w3 * f3.y;
    }
    for (; e < end; ++e) {
        uint2 m = ed[e];
        __hip_bfloat162 g = *(const __hip_bfloat162*)(hb + (size_t)(m.x & 0xFFFFu) * DOUT + col);
        int d = m.x >> 16;
        float w = __uint_as_float(m.y) * (d == 0 ? a0 : (d == 1 ? a1 : a2));
        float2 f = __bfloat1622float2(g);
        acc0 += w * f.x; acc1 += w * f.y;
    }
    __hip_bfloat162 o;
    o.x = __float2bfloat16(acc0 + bcc0);
    o.y = __float2bfloat16(acc1 + bcc1);
    *(__hip_bfloat162*)(aggcb + (size_t)n * DOUT + col) = o;
}

// ---------------- fused MFMA GEMM: C = sigmoid(A1@B1 + A2@B2), bf16 in, f32+bf16 out ---
// 128x128 tile, 4 waves (2x2), each wave 64x64 via 4x4 mfma_f32_16x16x32_bf16 frags.
// BT operands pre-transposed [N][K] so both frag loads are contiguous ds_read_b128.
__global__ __launch_bounds__(256) void k_mm(const __hip_bfloat16* __restrict__ A1,
                                            const __hip_bfloat16* __restrict__ BT1,
                                            const __hip_bfloat16* __restrict__ A2,
                                            const __hip_bfloat16* __restrict__ BT2,
                                            float* __restrict__ C,
                                            __hip_bfloat16* __restrict__ Cb,
                                            int M, int K1, int K2) {
    __shared__ short As[128][40];   // stride 40 (80B): bank-starts spread 8-periodic -> conflict-free
    __shared__ short Bs[128][40];
    int tid = threadIdx.x;
    int lane = tid & 63;
    int w = tid >> 6;
    int wr = (w >> 1) * 64, wc = (w & 1) * 64;
    int lr = lane & 15, kg = lane >> 4;
    int row0 = blockIdx.x * 128;

    f32x4 acc[4][4];
#pragma unroll
    for (int mi = 0; mi < 4; ++mi)
#pragma unroll
        for (int ni = 0; ni < 4; ++ni) acc[mi][ni] = (f32x4){0.f, 0.f, 0.f, 0.f};

#pragma unroll
    for (int seg = 0; seg < 2; ++seg) {
        const __hip_bfloat16* A = seg ? A2 : A1;
        const __hip_bfloat16* BT = seg ? BT2 : BT1;
        int K = seg ? K2 : K1;
        for (int k0 = 0; k0 < K; k0 += 32) {
#pragma unroll
            for (int j = 0; j < 2; ++j) {           // stage A tile: 512 x 16B chunks
                int c = tid + j * 256;
                int r = c >> 2, kc = (c & 3) * 8;
                bf16x8 g = {};
                int gr = row0 + r;
                if (gr < M) g = *(const bf16x8*)(A + (size_t)gr * K + k0 + kc);
                *(bf16x8*)&As[r][kc] = g;
            }
#pragma unroll
            for (int j = 0; j < 2; ++j) {           // stage BT tile
                int c = tid + j * 256;
                int r = c >> 2, kc = (c & 3) * 8;
                *(bf16x8*)&Bs[r][kc] = *(const bf16x8*)(BT + (size_t)r * K + k0 + kc);
            }
            __syncthreads();
            bf16x8 af[4], bfr[4];
#pragma unroll
            for (int i = 0; i < 4; ++i) {
                af[i]  = *(const bf16x8*)&As[wr + i * 16 + lr][kg * 8];
                bfr[i] = *(const bf16x8*)&Bs[wc + i * 16 + lr][kg * 8];
            }
#pragma unroll
            for (int mi = 0; mi < 4; ++mi)
#pragma unroll
                for (int ni = 0; ni < 4; ++ni)
                    acc[mi][ni] = __builtin_amdgcn_mfma_f32_16x16x32_bf16(
                        af[mi], bfr[ni], acc[mi][ni], 0, 0, 0);
            __syncthreads();
        }
    }

#pragma unroll
    for (int mi = 0; mi < 4; ++mi) {
#pragma unroll
        for (int r = 0; r < 4; ++r) {
            int row = row0 + wr + mi * 16 + kg * 4 + r;   // C/D: row=(lane>>4)*4+reg
            if (row < M) {
#pragma unroll
                for (int ni = 0; ni < 4; ++ni) {
                    int col = wc + ni * 16 + lr;          // C/D: col=lane&15
                    float v = acc[mi][ni][r];
                    v = 1.f / (1.f + __expf(-v));
                    C[(size_t)row * DOUT + col] = v;
                    Cb[(size_t)row * DOUT + col] = __float2bfloat16(v);
                }
            }
        }
    }
}

// ---------------- masked loss + accuracy (no global atomics) ----------------
__global__ __launch_bounds__(256) void k_loss(const float* __restrict__ h,
                                              const float* __restrict__ label,
                                              const int* __restrict__ idx,
                                              const float* __restrict__ u,
                                              const float* __restrict__ Wc,
                                              const float* __restrict__ bb,
                                              float* __restrict__ blockpart, int Mtot) {
    __shared__ float sl[4], sc2[4];
    int wid = threadIdx.x >> 6;
    int lane = threadIdx.x & 63;
    int gw = blockIdx.x * 4 + wid;
    int nw = gridDim.x * 4;
    float uv0 = u[lane], uv1 = u[64 + lane];
    float wc00 = Wc[lane * 2 + 0], wc01 = Wc[lane * 2 + 1];
    float wc10 = Wc[(lane + 64) * 2 + 0], wc11 = Wc[(lane + 64) * 2 + 1];
    float b0 = bb[0], b1 = bb[1];
    float lsum = 0.f, csum = 0.f;
    for (int w = gw; w < Mtot; w += nw) {
        int node = idx[w];
        float v0 = h[(size_t)node * DOUT + lane];
        float v1 = h[(size_t)node * DOUT + 64 + lane];
        float ps = v0 * uv0 + v1 * uv1;
        float p0 = v0 * wc00 + v1 * wc10;
        float p1 = v0 * wc01 + v1 * wc11;
#pragma unroll
        for (int o = 32; o > 0; o >>= 1) {
            ps += __shfl_xor(ps, o, 64);
            p0 += __shfl_xor(p0, o, 64);
            p1 += __shfl_xor(p1, o, 64);
        }
        if (lane == 0) {
            float y0 = label[(size_t)node * NCLS + 0];
            float y1 = label[(size_t)node * NCLS + 1];
            lsum += softplusf(-(y0 * ps)) + softplusf(-(y1 * ps));
            float l0 = p0 + b0, l1 = p1 + b1;
            int pred = (l1 > l0) ? 1 : 0;
            int truth = (y1 > y0) ? 1 : 0;
            csum += (pred == truth) ? 1.f : 0.f;
        }
    }
    if (lane == 0) { sl[wid] = lsum; sc2[wid] = csum; }
    __syncthreads();
    if (threadIdx.x == 0) {
        blockpart[blockIdx.x * 2 + 0] = sl[0] + sl[1] + sl[2] + sl[3];
        blockpart[blockIdx.x * 2 + 1] = sc2[0] + sc2[1] + sc2[2] + sc2[3];
    }
}

__global__ __launch_bounds__(256) void k_final(const float* __restrict__ bp,
                                               float* __restrict__ out, int nb) {
    __shared__ float sl[256], sc2[256];
    int t = threadIdx.x;
    float l = 0.f, c = 0.f;
    for (int i = t; i < nb; i += 256) { l += bp[i * 2]; c += bp[i * 2 + 1]; }
    sl[t] = l; sc2[t] = c;
    __syncthreads();
    for (int o = 128; o > 0; o >>= 1) {
        if (t < o) { sl[t] += sl[t + o]; sc2[t] += sc2[t + o]; }
        __syncthreads();
    }
    if (t == 0) { out[0] = sl[0]; out[1] = sc2[0] * (1.0f / NMASK); }
}

// ---------------- launch ----------------
extern "C" void kernel_launch(void* const* d_in, const int* in_sizes, int n_in,
                              void* d_out, int out_size, void* d_ws, size_t ws_size,
                              hipStream_t stream) {
    const float* x      = (const float*)d_in[0];
    const float* label  = (const float*)d_in[1];
    const int*   idx    = (const int*)d_in[2];
    const int*   src    = (const int*)d_in[3];
    const int*   dst    = (const int*)d_in[4];
    const float* vals   = (const float*)d_in[5];
    const float* h0     = (const float*)d_in[6];
    const float* Ws     = (const float*)d_in[7];
    const float* Vs     = (const float*)d_in[8];
    const float* alphas = (const float*)d_in[9];
    const float* Wc     = (const float*)d_in[10];
    const float* bb     = (const float*)d_in[11];
    const float* u      = (const float*)d_in[12];
    float* out = (float*)d_out;

    char* p = (char*)d_ws;
    float*          hB    = (float*)p;          p += (size_t)N_NODES * DOUT * 4;  // 25.6 MB
    __hip_bfloat16* aggcb = (__hip_bfloat16*)p; p += (size_t)N_NODES * DOUT * 2;  // 12.8 MB
    __hip_bfloat16* xb    = (__hip_bfloat16*)p; p += (size_t)N_NODES * DIN * 2;   // 25.6 MB
    __hip_bfloat16* hbf   = (__hip_bfloat16*)p; p += (size_t)N_NODES * DOUT * 2;  // 12.8 MB
    uint2*          ed    = (uint2*)p;          p += (size_t)TE * 8;              // 12 MB
    int*            offs  = (int*)p;            p += 200064;                      // N+1 ints
    __hip_bfloat16* WsT   = (__hip_bfloat16*)p; p += (size_t)NHOP * DOUT * DIN * 2;  // 128 KB
    __hip_bfloat16* VsT   = (__hip_bfloat16*)p; p += (size_t)NHOP * DOUT * DOUT * 2; // 64 KB
    float*          blockpart = (float*)p;      p += LOSS_BLOCKS * 2 * 4;
    // CSR-build scratch aliases hB (all dead before first k_mm writes hB)
    uint2* ebkt  = (uint2*)hB;                            // 12 MB
    int*   bh    = (int*)((char*)hB + (size_t)TE * 8);    // 576 KB
    int*   sc    = bh + BHN;                              // 576 KB
    int*   bsums = sc + BHN;

    // bucket-binned CSR build (reused for both hops)
    k_bhist<<<NBLKA, 256, 0, stream>>>(dst, bh);
    k_scanA<<<SCANBLKS, SCT, 0, stream>>>(bh, sc, bsums, BHN);
    k_scanB<<<1, SCT, 0, stream>>>(bsums, SCANBLKS);
    k_scanC<<<SCANBLKS, SCT, 0, stream>>>(sc, bsums, BHN);
    k_bbin<<<NBLKA, 256, 0, stream>>>(src, dst, vals, sc, ebkt);
    k_bsort<<<NBUCK, 256, 0, stream>>>(ebkt, sc, ed, offs);

    // bf16 conversions: h0 (first-hop gather), x (GEMM A1), weights (transposed)
    k_cvt<<<(N_NODES * DOUT / 2 + 255) / 256, 256, 0, stream>>>(h0, hbf, N_NODES * DOUT / 2);
    k_cvt<<<(N_NODES * DIN / 2 + 255) / 256, 256, 0, stream>>>(x, xb, N_NODES * DIN / 2);
    k_tw<<<(NHOP * (DIN * DOUT + DOUT * DOUT) + 255) / 256, 256, 0, stream>>>(Ws, Vs, WsT, VsT);

    const int MMBLK = (N_NODES + 127) / 128;  // 391
    for (int hop = 0; hop < NHOP; ++hop) {
        k_agg<<<(N_NODES + 3) / 4, 256, 0, stream>>>(hbf, ed, offs, alphas + hop * NDEV, aggcb);
        // hB/hbf = sigmoid(xb @ W + aggcb @ V), fused
        k_mm<<<MMBLK, 256, 0, stream>>>(xb, WsT + (size_t)hop * DOUT * DIN,
                                        aggcb, VsT + (size_t)hop * DOUT * DOUT,
                                        hB, hbf, N_NODES, DIN, DOUT);
    }

    k_loss<<<LOSS_BLOCKS, 256, 0, stream>>>(hB, label, idx, u, Wc, bb, blockpart, NMASK);
    k_final<<<1, 256, 0, stream>>>(blockpart, out, LOSS_BLOCKS);
}

// Round 6
// 277.110 us; speedup vs baseline: 3.3980x; 1.0031x over previous
//
#include <hip/hip_runtime.h>
#include <hip/hip_bf16.h>

#define N_NODES 50000
#define DIN     256
#define DOUT    128
#define NCLS    2
#define NHOP    2
#define NDEV    3
#define EDG     500000
#define TE      (NDEV*EDG)
#define NMASK   10000
#define LOSS_BLOCKS 100

#define BUCK    64
#define NBUCK   782                  // ceil(50000/64)
#define CH      8192                 // edges per binning block
#define NBLKA   184                  // ceil(TE/CH)
#define BHN     (NBUCK*NBLKA)        // 143888
#define SCT     512
#define SCANBLKS ((BHN + SCT - 1) / SCT)   // 282

typedef __attribute__((ext_vector_type(8))) short bf16x8;   // 8 bf16 = 4 VGPRs
typedef __attribute__((ext_vector_type(4))) float f32x4;

__device__ __forceinline__ float softplusf(float a) {
    return fmaxf(a, 0.f) + log1pf(expf(-fabsf(a)));
}

// ---------------- bucket-binned CSR build (write-amp ~1x) ----------------

__global__ __launch_bounds__(256) void k_bhist(const int* __restrict__ dst,
                                               int* __restrict__ bh) {
    __shared__ int hist[NBUCK];
    int blk = blockIdx.x, tid = threadIdx.x;
    for (int i = tid; i < NBUCK; i += 256) hist[i] = 0;
    __syncthreads();
    int base = blk * CH;
    int lim = min(base + CH, TE);
    for (int i = base + tid; i < lim; i += 256) atomicAdd(&hist[dst[i] >> 6], 1);
    __syncthreads();
    for (int i = tid; i < NBUCK; i += 256) bh[(size_t)i * NBLKA + blk] = hist[i];
}

__global__ __launch_bounds__(SCT) void k_scanA(const int* __restrict__ in,
                                               int* __restrict__ out,
                                               int* __restrict__ bsums, int n) {
    __shared__ int s[SCT];
    int tid = threadIdx.x, gid = blockIdx.x * SCT + tid;
    int v = (gid < n) ? in[gid] : 0;
    s[tid] = v; __syncthreads();
    for (int o = 1; o < SCT; o <<= 1) {
        int t = (tid >= o) ? s[tid - o] : 0;
        __syncthreads();
        s[tid] += t;
        __syncthreads();
    }
    if (gid < n) out[gid] = s[tid] - v;          // exclusive
    if (tid == SCT - 1) bsums[blockIdx.x] = s[SCT - 1];
}

__global__ __launch_bounds__(SCT) void k_scanB(int* __restrict__ bsums, int nb) {
    __shared__ int s[SCT];
    int tid = threadIdx.x;
    int v = (tid < nb) ? bsums[tid] : 0;
    s[tid] = v; __syncthreads();
    for (int o = 1; o < SCT; o <<= 1) {
        int t = (tid >= o) ? s[tid - o] : 0;
        __syncthreads();
        s[tid] += t;
        __syncthreads();
    }
    if (tid < nb) bsums[tid] = s[tid] - v;       // exclusive
}

__global__ __launch_bounds__(SCT) void k_scanC(int* __restrict__ out,
                                               const int* __restrict__ bsums, int n) {
    int gid = blockIdx.x * SCT + threadIdx.x;
    if (gid < n) out[gid] += bsums[blockIdx.x];
}

// bin edges into bucket-grouped array; pack src(16) | dev(2)<<16 | dstlocal(6)<<18
__global__ __launch_bounds__(256) void k_bbin(const int* __restrict__ src,
                                              const int* __restrict__ dst,
                                              const float* __restrict__ vals,
                                              const int* __restrict__ sc,
                                              uint2* __restrict__ ebkt) {
    __shared__ int cur[NBUCK];
    int blk = blockIdx.x, tid = threadIdx.x;
    for (int i = tid; i < NBUCK; i += 256) cur[i] = sc[(size_t)i * NBLKA + blk];
    __syncthreads();
    int base = blk * CH;
    int lim = min(base + CH, TE);
    for (int i = base + tid; i < lim; i += 256) {
        int d = i / EDG;
        int n = dst[i];
        int bu = n >> 6;
        int pos = atomicAdd(&cur[bu], 1);
        ebkt[pos] = make_uint2((unsigned)src[i] | ((unsigned)d << 16) |
                               ((unsigned)(n & 63) << 18),
                               __float_as_uint(vals[i]));
    }
}

// per-bucket counting sort by node; emits per-hop {src, alpha*val} arrays + offsets
__global__ __launch_bounds__(256) void k_bsort(const uint2* __restrict__ ebkt,
                                               const int* __restrict__ sc,
                                               const float* __restrict__ alphas,
                                               uint2* __restrict__ edh0,
                                               uint2* __restrict__ edh1,
                                               int* __restrict__ offs) {
    __shared__ int cnt[BUCK], start[BUCK + 1], cur[BUCK];
    int b = blockIdx.x, tid = threadIdx.x;
    float a00 = alphas[0], a01 = alphas[1], a02 = alphas[2];
    float a10 = alphas[3], a11 = alphas[4], a12 = alphas[5];
    int beg = sc[(size_t)b * NBLKA];
    int end = (b + 1 < NBUCK) ? sc[(size_t)(b + 1) * NBLKA] : TE;
    if (tid < BUCK) { cnt[tid] = 0; cur[tid] = 0; }
    __syncthreads();
    for (int e = beg + tid; e < end; e += 256)
        atomicAdd(&cnt[(ebkt[e].x >> 18) & 63], 1);
    __syncthreads();
    if (tid == 0) {
        int acc = 0;
        for (int i = 0; i < BUCK; ++i) { start[i] = acc; acc += cnt[i]; }
        start[BUCK] = acc;
    }
    __syncthreads();
    if (tid < BUCK) {
        int n = b * BUCK + tid;
        if (n < N_NODES) offs[n] = beg + start[tid];
    }
    if (b == 0 && tid == 255) offs[N_NODES] = TE;
    for (int e = beg + tid; e < end; e += 256) {
        uint2 v = ebkt[e];
        int dl = (v.x >> 18) & 63;
        int pos = beg + start[dl] + atomicAdd(&cur[dl], 1);
        unsigned s = v.x & 0xFFFFu;
        int d = (v.x >> 16) & 3;
        float val = __uint_as_float(v.y);
        float w0 = val * (d == 0 ? a00 : (d == 1 ? a01 : a02));
        float w1 = val * (d == 0 ? a10 : (d == 1 ? a11 : a12));
        edh0[pos] = make_uint2(s, __float_as_uint(w0));
        edh1[pos] = make_uint2(s, __float_as_uint(w1));
    }
}

// fp32 -> bf16 copy (float2 per thread)
__global__ void k_cvt(const float* __restrict__ in, __hip_bfloat16* __restrict__ out, int n2) {
    int i = blockIdx.x * blockDim.x + threadIdx.x;
    if (i >= n2) return;
    float2 f = ((const float2*)in)[i];
    __hip_bfloat162 b;
    b.x = __float2bfloat16(f.x);
    b.y = __float2bfloat16(f.y);
    ((__hip_bfloat162*)out)[i] = b;
}

// weight transpose+convert: WsT[hop][n][k] = bf16(Ws[hop][k][n]); same for Vs
__global__ void k_tw(const float* __restrict__ Ws, const float* __restrict__ Vs,
                     __hip_bfloat16* __restrict__ WsT, __hip_bfloat16* __restrict__ VsT) {
    int i = blockIdx.x * 256 + threadIdx.x;
    if (i < NHOP * DIN * DOUT) {
        int hop = i / (DIN * DOUT);
        int r = i % (DIN * DOUT);
        int k = r >> 7, n = r & 127;
        WsT[(size_t)hop * DOUT * DIN + (size_t)n * DIN + k] = __float2bfloat16(Ws[i]);
    } else {
        int j = i - NHOP * DIN * DOUT;
        if (j < NHOP * DOUT * DOUT) {
            int hop = j / (DOUT * DOUT);
            int r = j % (DOUT * DOUT);
            int k = r >> 7, n = r & 127;
            VsT[(size_t)hop * DOUT * DOUT + (size_t)n * DOUT + k] = __float2bfloat16(Vs[j]);
        }
    }
}

// ---------------- sparse aggregation: one wave per node, 2 edges/wave ----------------
// lanes 0-31: even edges, lanes 32-63: odd edges; each lane owns 4 cols (bf16x4 = 8B).
__global__ __launch_bounds__(256) void k_agg(const __hip_bfloat16* __restrict__ hb,
                                             const uint2* __restrict__ edh,
                                             const int* __restrict__ offs,
                                             __hip_bfloat16* __restrict__ aggcb) {
    int wid = threadIdx.x >> 6;
    int lane = threadIdx.x & 63;
    int n = blockIdx.x * 4 + wid;
    if (n >= N_NODES) return;
    int half = lane >> 5;        // 0 = even edge, 1 = odd edge
    int c8 = lane & 31;          // 8-byte chunk of the 256B row
    int beg = offs[n], end = offs[n + 1];
    float a0 = 0.f, a1 = 0.f, a2 = 0.f, a3 = 0.f;
    int e = beg;
    for (; e + 8 <= end; e += 8) {
#pragma unroll
        for (int p = 0; p < 4; ++p) {
            uint2 q = edh[e + p * 2 + half];           // {src, w}
            uint2 g = *(const uint2*)(hb + (size_t)q.x * DOUT + c8 * 4);
            float wt = __uint_as_float(q.y);
            a0 += wt * __uint_as_float(g.x << 16);
            a1 += wt * __uint_as_float(g.x & 0xFFFF0000u);
            a2 += wt * __uint_as_float(g.y << 16);
            a3 += wt * __uint_as_float(g.y & 0xFFFF0000u);
        }
    }
    for (; e + 2 <= end; e += 2) {
        uint2 q = edh[e + half];
        uint2 g = *(const uint2*)(hb + (size_t)q.x * DOUT + c8 * 4);
        float wt = __uint_as_float(q.y);
        a0 += wt * __uint_as_float(g.x << 16);
        a1 += wt * __uint_as_float(g.x & 0xFFFF0000u);
        a2 += wt * __uint_as_float(g.y << 16);
        a3 += wt * __uint_as_float(g.y & 0xFFFF0000u);
    }
    if (e < end && half == 0) {                        // odd-degree tail
        uint2 q = edh[e];
        uint2 g = *(const uint2*)(hb + (size_t)q.x * DOUT + c8 * 4);
        float wt = __uint_as_float(q.y);
        a0 += wt * __uint_as_float(g.x << 16);
        a1 += wt * __uint_as_float(g.x & 0xFFFF0000u);
        a2 += wt * __uint_as_float(g.y << 16);
        a3 += wt * __uint_as_float(g.y & 0xFFFF0000u);
    }
    a0 += __shfl_xor(a0, 32, 64);
    a1 += __shfl_xor(a1, 32, 64);
    a2 += __shfl_xor(a2, 32, 64);
    a3 += __shfl_xor(a3, 32, 64);
    if (half == 0) {
        union { __hip_bfloat16 h[4]; ushort4 u; } pk;
        pk.h[0] = __float2bfloat16(a0);
        pk.h[1] = __float2bfloat16(a1);
        pk.h[2] = __float2bfloat16(a2);
        pk.h[3] = __float2bfloat16(a3);
        *(ushort4*)(aggcb + (size_t)n * DOUT + c8 * 4) = pk.u;
    }
}

// ---------------- fused MFMA GEMM: Cb = sigmoid(A1@B1 + A2@B2), bf16 in/out ----------
// 128x128 tile, 4 waves (2x2), each wave 64x64 via 4x4 mfma_f32_16x16x32_bf16 frags.
__global__ __launch_bounds__(256) void k_mm(const __hip_bfloat16* __restrict__ A1,
                                            const __hip_bfloat16* __restrict__ BT1,
                                            const __hip_bfloat16* __restrict__ A2,
                                            const __hip_bfloat16* __restrict__ BT2,
                                            __hip_bfloat16* __restrict__ Cb,
                                            int M, int K1, int K2) {
    __shared__ short As[128][40];   // stride 40: bank-starts spread 8-periodic
    __shared__ short Bs[128][40];
    int tid = threadIdx.x;
    int lane = tid & 63;
    int w = tid >> 6;
    int wr = (w >> 1) * 64, wc = (w & 1) * 64;
    int lr = lane & 15, kg = lane >> 4;
    int row0 = blockIdx.x * 128;

    f32x4 acc[4][4];
#pragma unroll
    for (int mi = 0; mi < 4; ++mi)
#pragma unroll
        for (int ni = 0; ni < 4; ++ni) acc[mi][ni] = (f32x4){0.f, 0.f, 0.f, 0.f};

#pragma unroll
    for (int seg = 0; seg < 2; ++seg) {
        const __hip_bfloat16* A = seg ? A2 : A1;
        const __hip_bfloat16* BT = seg ? BT2 : BT1;
        int K = seg ? K2 : K1;
        for (int k0 = 0; k0 < K; k0 += 32) {
#pragma unroll
            for (int j = 0; j < 2; ++j) {           // stage A tile: 512 x 16B chunks
                int c = tid + j * 256;
                int r = c >> 2, kc = (c & 3) * 8;
                bf16x8 g = {};
                int gr = row0 + r;
                if (gr < M) g = *(const bf16x8*)(A + (size_t)gr * K + k0 + kc);
                *(bf16x8*)&As[r][kc] = g;
            }
#pragma unroll
            for (int j = 0; j < 2; ++j) {           // stage BT tile
                int c = tid + j * 256;
                int r = c >> 2, kc = (c & 3) * 8;
                *(bf16x8*)&Bs[r][kc] = *(const bf16x8*)(BT + (size_t)r * K + k0 + kc);
            }
            __syncthreads();
            bf16x8 af[4], bfr[4];
#pragma unroll
            for (int i = 0; i < 4; ++i) {
                af[i]  = *(const bf16x8*)&As[wr + i * 16 + lr][kg * 8];
                bfr[i] = *(const bf16x8*)&Bs[wc + i * 16 + lr][kg * 8];
            }
#pragma unroll
            for (int mi = 0; mi < 4; ++mi)
#pragma unroll
                for (int ni = 0; ni < 4; ++ni)
                    acc[mi][ni] = __builtin_amdgcn_mfma_f32_16x16x32_bf16(
                        af[mi], bfr[ni], acc[mi][ni], 0, 0, 0);
            __syncthreads();
        }
    }

#pragma unroll
    for (int mi = 0; mi < 4; ++mi) {
#pragma unroll
        for (int r = 0; r < 4; ++r) {
            int row = row0 + wr + mi * 16 + kg * 4 + r;   // C/D: row=(lane>>4)*4+reg
            if (row < M) {
#pragma unroll
                for (int ni = 0; ni < 4; ++ni) {
                    int col = wc + ni * 16 + lr;          // C/D: col=lane&15
                    float v = acc[mi][ni][r];
                    v = 1.f / (1.f + __expf(-v));
                    Cb[(size_t)row * DOUT + col] = __float2bfloat16(v);
                }
            }
        }
    }
}

// ---------------- masked loss + accuracy (bf16 h, no global atomics) ----------------
__global__ __launch_bounds__(256) void k_loss(const __hip_bfloat16* __restrict__ h,
                                              const float* __restrict__ label,
                                              const int* __restrict__ idx,
                                              const float* __restrict__ u,
                                              const float* __restrict__ Wc,
                                              const float* __restrict__ bb,
                                              float* __restrict__ blockpart, int Mtot) {
    __shared__ float sl[4], sc2[4];
    int wid = threadIdx.x >> 6;
    int lane = threadIdx.x & 63;
    int gw = blockIdx.x * 4 + wid;
    int nw = gridDim.x * 4;
    float uv0 = u[lane], uv1 = u[64 + lane];
    float wc00 = Wc[lane * 2 + 0], wc01 = Wc[lane * 2 + 1];
    float wc10 = Wc[(lane + 64) * 2 + 0], wc11 = Wc[(lane + 64) * 2 + 1];
    float b0 = bb[0], b1 = bb[1];
    float lsum = 0.f, csum = 0.f;
    for (int w = gw; w < Mtot; w += nw) {
        int node = idx[w];
        float v0 = __bfloat162float(h[(size_t)node * DOUT + lane]);
        float v1 = __bfloat162float(h[(size_t)node * DOUT + 64 + lane]);
        float ps = v0 * uv0 + v1 * uv1;
        float p0 = v0 * wc00 + v1 * wc10;
        float p1 = v0 * wc01 + v1 * wc11;
#pragma unroll
        for (int o = 32; o > 0; o >>= 1) {
            ps += __shfl_xor(ps, o, 64);
            p0 += __shfl_xor(p0, o, 64);
            p1 += __shfl_xor(p1, o, 64);
        }
        if (lane == 0) {
            float y0 = label[(size_t)node * NCLS + 0];
            float y1 = label[(size_t)node * NCLS + 1];
            lsum += softplusf(-(y0 * ps)) + softplusf(-(y1 * ps));
            float l0 = p0 + b0, l1 = p1 + b1;
            int pred = (l1 > l0) ? 1 : 0;
            int truth = (y1 > y0) ? 1 : 0;
            csum += (pred == truth) ? 1.f : 0.f;
        }
    }
    if (lane == 0) { sl[wid] = lsum; sc2[wid] = csum; }
    __syncthreads();
    if (threadIdx.x == 0) {
        blockpart[blockIdx.x * 2 + 0] = sl[0] + sl[1] + sl[2] + sl[3];
        blockpart[blockIdx.x * 2 + 1] = sc2[0] + sc2[1] + sc2[2] + sc2[3];
    }
}

__global__ __launch_bounds__(256) void k_final(const float* __restrict__ bp,
                                               float* __restrict__ out, int nb) {
    __shared__ float sl[256], sc2[256];
    int t = threadIdx.x;
    float l = 0.f, c = 0.f;
    for (int i = t; i < nb; i += 256) { l += bp[i * 2]; c += bp[i * 2 + 1]; }
    sl[t] = l; sc2[t] = c;
    __syncthreads();
    for (int o = 128; o > 0; o >>= 1) {
        if (t < o) { sl[t] += sl[t + o]; sc2[t] += sc2[t + o]; }
        __syncthreads();
    }
    if (t == 0) { out[0] = sl[0]; out[1] = sc2[0] * (1.0f / NMASK); }
}

// ---------------- launch ----------------
extern "C" void kernel_launch(void* const* d_in, const int* in_sizes, int n_in,
                              void* d_out, int out_size, void* d_ws, size_t ws_size,
                              hipStream_t stream) {
    const float* x      = (const float*)d_in[0];
    const float* label  = (const float*)d_in[1];
    const int*   idx    = (const int*)d_in[2];
    const int*   src    = (const int*)d_in[3];
    const int*   dst    = (const int*)d_in[4];
    const float* vals   = (const float*)d_in[5];
    const float* h0     = (const float*)d_in[6];
    const float* Ws     = (const float*)d_in[7];
    const float* Vs     = (const float*)d_in[8];
    const float* alphas = (const float*)d_in[9];
    const float* Wc     = (const float*)d_in[10];
    const float* bb     = (const float*)d_in[11];
    const float* u      = (const float*)d_in[12];
    float* out = (float*)d_out;

    char* p = (char*)d_ws;
    __hip_bfloat16* aggcb = (__hip_bfloat16*)p; p += (size_t)N_NODES * DOUT * 2;  // 12.8 MB
    __hip_bfloat16* xb    = (__hip_bfloat16*)p; p += (size_t)N_NODES * DIN * 2;   // 25.6 MB
    __hip_bfloat16* hbf   = (__hip_bfloat16*)p; p += (size_t)N_NODES * DOUT * 2;  // 12.8 MB
    uint2*          edh0  = (uint2*)p;          p += (size_t)TE * 8;              // 12 MB
    uint2*          edh1  = (uint2*)p;          p += (size_t)TE * 8;              // 12 MB
    int*            offs  = (int*)p;            p += 200064;                      // N+1 ints
    __hip_bfloat16* WsT   = (__hip_bfloat16*)p; p += (size_t)NHOP * DOUT * DIN * 2;  // 128 KB
    __hip_bfloat16* VsT   = (__hip_bfloat16*)p; p += (size_t)NHOP * DOUT * DOUT * 2; // 64 KB
    float*          blockpart = (float*)p;      p += LOSS_BLOCKS * 2 * 4;
    // CSR-build scratch aliases xb (xb written by k_cvt AFTER k_bsort; stream-serial)
    uint2* ebkt  = (uint2*)xb;                            // 12 MB
    int*   bh    = (int*)((char*)xb + (size_t)TE * 8);    // 576 KB
    int*   sc    = bh + BHN;                              // 576 KB
    int*   bsums = sc + BHN;

    // bucket-binned CSR build (per-hop prescaled weights; reused for both hops)
    k_bhist<<<NBLKA, 256, 0, stream>>>(dst, bh);
    k_scanA<<<SCANBLKS, SCT, 0, stream>>>(bh, sc, bsums, BHN);
    k_scanB<<<1, SCT, 0, stream>>>(bsums, SCANBLKS);
    k_scanC<<<SCANBLKS, SCT, 0, stream>>>(sc, bsums, BHN);
    k_bbin<<<NBLKA, 256, 0, stream>>>(src, dst, vals, sc, ebkt);
    k_bsort<<<NBUCK, 256, 0, stream>>>(ebkt, sc, alphas, edh0, edh1, offs);

    // bf16 conversions: h0 (first-hop gather), x (GEMM A1), weights (transposed)
    k_cvt<<<(N_NODES * DOUT / 2 + 255) / 256, 256, 0, stream>>>(h0, hbf, N_NODES * DOUT / 2);
    k_cvt<<<(N_NODES * DIN / 2 + 255) / 256, 256, 0, stream>>>(x, xb, N_NODES * DIN / 2);
    k_tw<<<(NHOP * (DIN * DOUT + DOUT * DOUT) + 255) / 256, 256, 0, stream>>>(Ws, Vs, WsT, VsT);

    const int MMBLK = (N_NODES + 127) / 128;  // 391
    for (int hop = 0; hop < NHOP; ++hop) {
        k_agg<<<(N_NODES + 3) / 4, 256, 0, stream>>>(hbf, hop ? edh1 : edh0, offs, aggcb);
        // hbf = sigmoid(xb @ W + aggcb @ V), fused
        k_mm<<<MMBLK, 256, 0, stream>>>(xb, WsT + (size_t)hop * DOUT * DIN,
                                        aggcb, VsT + (size_t)hop * DOUT * DOUT,
                                        hbf, N_NODES, DIN, DOUT);
    }

    k_loss<<<LOSS_BLOCKS, 256, 0, stream>>>(hbf, label, idx, u, Wc, bb, blockpart, NMASK);
    k_final<<<1, 256, 0, stream>>>(blockpart, out, LOSS_BLOCKS);
}

// Round 7
// 256.498 us; speedup vs baseline: 3.6711x; 1.0804x over previous
//
#include <hip/hip_runtime.h>
#include <hip/hip_bf16.h>

#define N_NODES 50000
#define DIN     256
#define DOUT    128
#define NCLS    2
#define NHOP    2
#define NDEV    3
#define EDG     500000
#define TE      (NDEV*EDG)
#define NMASK   10000
#define LOSS_BLOCKS 100

#define BUCK    64
#define NBUCK   782                  // ceil(50000/64)
#define CH      8192                 // edges per binning block
#define NBLKA   184                  // ceil(TE/CH)
#define BHN     (NBUCK*NBLKA)        // 143888
#define SCT     512
#define SCANBLKS ((BHN + SCT - 1) / SCT)   // 282

typedef __attribute__((ext_vector_type(8))) short bf16x8;   // 8 bf16 = 4 VGPRs
typedef __attribute__((ext_vector_type(4))) float f32x4;
typedef __attribute__((ext_vector_type(2))) float f32x2;

__device__ __forceinline__ float softplusf(float a) {
    return fmaxf(a, 0.f) + log1pf(expf(-fabsf(a)));
}

// fp8 e4m3 (OCP on gfx950) helpers via HW pack/unpack
__device__ __forceinline__ f32x2 fp8lo(unsigned g) {
    return __builtin_amdgcn_cvt_pk_f32_fp8(g, false);
}
__device__ __forceinline__ f32x2 fp8hi(unsigned g) {
    return __builtin_amdgcn_cvt_pk_f32_fp8(g, true);
}
__device__ __forceinline__ unsigned char fp8enc1(float v) {
    return (unsigned char)(__builtin_amdgcn_cvt_pk_fp8_f32(v, v, 0, false) & 0xFF);
}

// ---------------- bucket-binned CSR build (write-amp ~1x) ----------------

__global__ __launch_bounds__(256) void k_bhist(const int* __restrict__ dst,
                                               int* __restrict__ bh) {
    __shared__ int hist[NBUCK];
    int blk = blockIdx.x, tid = threadIdx.x;
    for (int i = tid; i < NBUCK; i += 256) hist[i] = 0;
    __syncthreads();
    int base = blk * CH;
    int lim = min(base + CH, TE);
    for (int i = base + tid; i < lim; i += 256) atomicAdd(&hist[dst[i] >> 6], 1);
    __syncthreads();
    for (int i = tid; i < NBUCK; i += 256) bh[(size_t)i * NBLKA + blk] = hist[i];
}

__global__ __launch_bounds__(SCT) void k_scanA(const int* __restrict__ in,
                                               int* __restrict__ out,
                                               int* __restrict__ bsums, int n) {
    __shared__ int s[SCT];
    int tid = threadIdx.x, gid = blockIdx.x * SCT + tid;
    int v = (gid < n) ? in[gid] : 0;
    s[tid] = v; __syncthreads();
    for (int o = 1; o < SCT; o <<= 1) {
        int t = (tid >= o) ? s[tid - o] : 0;
        __syncthreads();
        s[tid] += t;
        __syncthreads();
    }
    if (gid < n) out[gid] = s[tid] - v;          // exclusive
    if (tid == SCT - 1) bsums[blockIdx.x] = s[SCT - 1];
}

__global__ __launch_bounds__(SCT) void k_scanB(int* __restrict__ bsums, int nb) {
    __shared__ int s[SCT];
    int tid = threadIdx.x;
    int v = (tid < nb) ? bsums[tid] : 0;
    s[tid] = v; __syncthreads();
    for (int o = 1; o < SCT; o <<= 1) {
        int t = (tid >= o) ? s[tid - o] : 0;
        __syncthreads();
        s[tid] += t;
        __syncthreads();
    }
    if (tid < nb) bsums[tid] = s[tid] - v;       // exclusive
}

__global__ __launch_bounds__(SCT) void k_scanC(int* __restrict__ out,
                                               const int* __restrict__ bsums, int n) {
    int gid = blockIdx.x * SCT + threadIdx.x;
    if (gid < n) out[gid] += bsums[blockIdx.x];
}

// bin edges into bucket-grouped array; pack src(16) | dev(2)<<16 | dstlocal(6)<<18
__global__ __launch_bounds__(256) void k_bbin(const int* __restrict__ src,
                                              const int* __restrict__ dst,
                                              const float* __restrict__ vals,
                                              const int* __restrict__ sc,
                                              uint2* __restrict__ ebkt) {
    __shared__ int cur[NBUCK];
    int blk = blockIdx.x, tid = threadIdx.x;
    for (int i = tid; i < NBUCK; i += 256) cur[i] = sc[(size_t)i * NBLKA + blk];
    __syncthreads();
    int base = blk * CH;
    int lim = min(base + CH, TE);
    for (int i = base + tid; i < lim; i += 256) {
        int d = i / EDG;
        int n = dst[i];
        int bu = n >> 6;
        int pos = atomicAdd(&cur[bu], 1);
        ebkt[pos] = make_uint2((unsigned)src[i] | ((unsigned)d << 16) |
                               ((unsigned)(n & 63) << 18),
                               __float_as_uint(vals[i]));
    }
}

// per-bucket counting sort by node; emits per-hop {src, alpha*val} arrays + offsets
__global__ __launch_bounds__(256) void k_bsort(const uint2* __restrict__ ebkt,
                                               const int* __restrict__ sc,
                                               const float* __restrict__ alphas,
                                               uint2* __restrict__ edh0,
                                               uint2* __restrict__ edh1,
                                               int* __restrict__ offs) {
    __shared__ int cnt[BUCK], start[BUCK + 1], cur[BUCK];
    int b = blockIdx.x, tid = threadIdx.x;
    float a00 = alphas[0], a01 = alphas[1], a02 = alphas[2];
    float a10 = alphas[3], a11 = alphas[4], a12 = alphas[5];
    int beg = sc[(size_t)b * NBLKA];
    int end = (b + 1 < NBUCK) ? sc[(size_t)(b + 1) * NBLKA] : TE;
    if (tid < BUCK) { cnt[tid] = 0; cur[tid] = 0; }
    __syncthreads();
    for (int e = beg + tid; e < end; e += 256)
        atomicAdd(&cnt[(ebkt[e].x >> 18) & 63], 1);
    __syncthreads();
    if (tid == 0) {
        int acc = 0;
        for (int i = 0; i < BUCK; ++i) { start[i] = acc; acc += cnt[i]; }
        start[BUCK] = acc;
    }
    __syncthreads();
    if (tid < BUCK) {
        int n = b * BUCK + tid;
        if (n < N_NODES) offs[n] = beg + start[tid];
    }
    if (b == 0 && tid == 255) offs[N_NODES] = TE;
    for (int e = beg + tid; e < end; e += 256) {
        uint2 v = ebkt[e];
        int dl = (v.x >> 18) & 63;
        int pos = beg + start[dl] + atomicAdd(&cur[dl], 1);
        unsigned s = v.x & 0xFFFFu;
        int d = (v.x >> 16) & 3;
        float val = __uint_as_float(v.y);
        float w0 = val * (d == 0 ? a00 : (d == 1 ? a01 : a02));
        float w1 = val * (d == 0 ? a10 : (d == 1 ? a11 : a12));
        edh0[pos] = make_uint2(s, __float_as_uint(w0));
        edh1[pos] = make_uint2(s, __float_as_uint(w1));
    }
}

// fp32 -> bf16 copy (float2 per thread)
__global__ void k_cvt(const float* __restrict__ in, __hip_bfloat16* __restrict__ out, int n2) {
    int i = blockIdx.x * blockDim.x + threadIdx.x;
    if (i >= n2) return;
    float2 f = ((const float2*)in)[i];
    __hip_bfloat162 b;
    b.x = __float2bfloat16(f.x);
    b.y = __float2bfloat16(f.y);
    ((__hip_bfloat162*)out)[i] = b;
}

// fp32 -> fp8 e4m3 copy (float4 -> 4 bytes per thread)
__global__ void k_cvt8(const float* __restrict__ in, unsigned char* __restrict__ out, int n4) {
    int i = blockIdx.x * blockDim.x + threadIdx.x;
    if (i >= n4) return;
    float4 f = ((const float4*)in)[i];
    int r = 0;
    r = __builtin_amdgcn_cvt_pk_fp8_f32(f.x, f.y, r, false);
    r = __builtin_amdgcn_cvt_pk_fp8_f32(f.z, f.w, r, true);
    ((unsigned*)out)[i] = (unsigned)r;
}

// weight transpose+convert: WsT[hop][n][k] = bf16(Ws[hop][k][n]); same for Vs
__global__ void k_tw(const float* __restrict__ Ws, const float* __restrict__ Vs,
                     __hip_bfloat16* __restrict__ WsT, __hip_bfloat16* __restrict__ VsT) {
    int i = blockIdx.x * 256 + threadIdx.x;
    if (i < NHOP * DIN * DOUT) {
        int hop = i / (DIN * DOUT);
        int r = i % (DIN * DOUT);
        int k = r >> 7, n = r & 127;
        WsT[(size_t)hop * DOUT * DIN + (size_t)n * DIN + k] = __float2bfloat16(Ws[i]);
    } else {
        int j = i - NHOP * DIN * DOUT;
        if (j < NHOP * DOUT * DOUT) {
            int hop = j / (DOUT * DOUT);
            int r = j % (DOUT * DOUT);
            int k = r >> 7, n = r & 127;
            VsT[(size_t)hop * DOUT * DOUT + (size_t)n * DOUT + k] = __float2bfloat16(Vs[j]);
        }
    }
}

// ---------------- sparse aggregation: one wave per node, fp8 rows, 2 edges/wave ------
// lanes 0-31: even edges, lanes 32-63: odd edges; each lane owns 4 cols (4 fp8 = 4B).
__global__ __launch_bounds__(256) void k_agg(const unsigned char* __restrict__ h8,
                                             const uint2* __restrict__ edh,
                                             const int* __restrict__ offs,
                                             __hip_bfloat16* __restrict__ aggcb) {
    int wid = threadIdx.x >> 6;
    int lane = threadIdx.x & 63;
    int n = blockIdx.x * 4 + wid;
    if (n >= N_NODES) return;
    int half = lane >> 5;        // 0 = even edge, 1 = odd edge
    int c4 = lane & 31;          // 4-byte chunk of the 128B fp8 row
    int beg = offs[n], end = offs[n + 1];
    float a0 = 0.f, a1 = 0.f, a2 = 0.f, a3 = 0.f;
    int e = beg;
    for (; e + 8 <= end; e += 8) {
#pragma unroll
        for (int p = 0; p < 4; ++p) {
            uint2 q = edh[e + p * 2 + half];           // {src, w}
            unsigned g = *(const unsigned*)(h8 + (size_t)q.x * DOUT + c4 * 4);
            float wt = __uint_as_float(q.y);
            f32x2 lo = fp8lo(g), hi = fp8hi(g);
            a0 += wt * lo[0]; a1 += wt * lo[1];
            a2 += wt * hi[0]; a3 += wt * hi[1];
        }
    }
    for (; e + 2 <= end; e += 2) {
        uint2 q = edh[e + half];
        unsigned g = *(const unsigned*)(h8 + (size_t)q.x * DOUT + c4 * 4);
        float wt = __uint_as_float(q.y);
        f32x2 lo = fp8lo(g), hi = fp8hi(g);
        a0 += wt * lo[0]; a1 += wt * lo[1];
        a2 += wt * hi[0]; a3 += wt * hi[1];
    }
    if (e < end && half == 0) {                        // odd-degree tail
        uint2 q = edh[e];
        unsigned g = *(const unsigned*)(h8 + (size_t)q.x * DOUT + c4 * 4);
        float wt = __uint_as_float(q.y);
        f32x2 lo = fp8lo(g), hi = fp8hi(g);
        a0 += wt * lo[0]; a1 += wt * lo[1];
        a2 += wt * hi[0]; a3 += wt * hi[1];
    }
    a0 += __shfl_xor(a0, 32, 64);
    a1 += __shfl_xor(a1, 32, 64);
    a2 += __shfl_xor(a2, 32, 64);
    a3 += __shfl_xor(a3, 32, 64);
    if (half == 0) {
        union { __hip_bfloat16 h[4]; ushort4 u; } pk;
        pk.h[0] = __float2bfloat16(a0);
        pk.h[1] = __float2bfloat16(a1);
        pk.h[2] = __float2bfloat16(a2);
        pk.h[3] = __float2bfloat16(a3);
        *(ushort4*)(aggcb + (size_t)n * DOUT + c4 * 4) = pk.u;
    }
}

// ---------------- fused MFMA GEMM: h = sigmoid(A1@B1 + A2@B2), bf16 in --------------
// outputs: C8 (fp8, for next hop's gather) and/or Cbf (bf16, for loss).
__global__ __launch_bounds__(256) void k_mm(const __hip_bfloat16* __restrict__ A1,
                                            const __hip_bfloat16* __restrict__ BT1,
                                            const __hip_bfloat16* __restrict__ A2,
                                            const __hip_bfloat16* __restrict__ BT2,
                                            unsigned char* __restrict__ C8,
                                            __hip_bfloat16* __restrict__ Cbf,
                                            int M, int K1, int K2) {
    __shared__ short As[128][40];   // stride 40: bank-starts spread 8-periodic
    __shared__ short Bs[128][40];
    int tid = threadIdx.x;
    int lane = tid & 63;
    int w = tid >> 6;
    int wr = (w >> 1) * 64, wc = (w & 1) * 64;
    int lr = lane & 15, kg = lane >> 4;
    int row0 = blockIdx.x * 128;

    f32x4 acc[4][4];
#pragma unroll
    for (int mi = 0; mi < 4; ++mi)
#pragma unroll
        for (int ni = 0; ni < 4; ++ni) acc[mi][ni] = (f32x4){0.f, 0.f, 0.f, 0.f};

#pragma unroll
    for (int seg = 0; seg < 2; ++seg) {
        const __hip_bfloat16* A = seg ? A2 : A1;
        const __hip_bfloat16* BT = seg ? BT2 : BT1;
        int K = seg ? K2 : K1;
        for (int k0 = 0; k0 < K; k0 += 32) {
#pragma unroll
            for (int j = 0; j < 2; ++j) {           // stage A tile: 512 x 16B chunks
                int c = tid + j * 256;
                int r = c >> 2, kc = (c & 3) * 8;
                bf16x8 g = {};
                int gr = row0 + r;
                if (gr < M) g = *(const bf16x8*)(A + (size_t)gr * K + k0 + kc);
                *(bf16x8*)&As[r][kc] = g;
            }
#pragma unroll
            for (int j = 0; j < 2; ++j) {           // stage BT tile
                int c = tid + j * 256;
                int r = c >> 2, kc = (c & 3) * 8;
                *(bf16x8*)&Bs[r][kc] = *(const bf16x8*)(BT + (size_t)r * K + k0 + kc);
            }
            __syncthreads();
            bf16x8 af[4], bfr[4];
#pragma unroll
            for (int i = 0; i < 4; ++i) {
                af[i]  = *(const bf16x8*)&As[wr + i * 16 + lr][kg * 8];
                bfr[i] = *(const bf16x8*)&Bs[wc + i * 16 + lr][kg * 8];
            }
#pragma unroll
            for (int mi = 0; mi < 4; ++mi)
#pragma unroll
                for (int ni = 0; ni < 4; ++ni)
                    acc[mi][ni] = __builtin_amdgcn_mfma_f32_16x16x32_bf16(
                        af[mi], bfr[ni], acc[mi][ni], 0, 0, 0);
            __syncthreads();
        }
    }

#pragma unroll
    for (int mi = 0; mi < 4; ++mi) {
#pragma unroll
        for (int r = 0; r < 4; ++r) {
            int row = row0 + wr + mi * 16 + kg * 4 + r;   // C/D: row=(lane>>4)*4+reg
            if (row < M) {
#pragma unroll
                for (int ni = 0; ni < 4; ++ni) {
                    int col = wc + ni * 16 + lr;          // C/D: col=lane&15
                    float v = acc[mi][ni][r];
                    v = 1.f / (1.f + __expf(-v));
                    if (C8)  C8[(size_t)row * DOUT + col] = fp8enc1(v);
                    if (Cbf) Cbf[(size_t)row * DOUT + col] = __float2bfloat16(v);
                }
            }
        }
    }
}

// ---------------- masked loss + accuracy (bf16 h, no global atomics) ----------------
__global__ __launch_bounds__(256) void k_loss(const __hip_bfloat16* __restrict__ h,
                                              const float* __restrict__ label,
                                              const int* __restrict__ idx,
                                              const float* __restrict__ u,
                                              const float* __restrict__ Wc,
                                              const float* __restrict__ bb,
                                              float* __restrict__ blockpart, int Mtot) {
    __shared__ float sl[4], sc2[4];
    int wid = threadIdx.x >> 6;
    int lane = threadIdx.x & 63;
    int gw = blockIdx.x * 4 + wid;
    int nw = gridDim.x * 4;
    float uv0 = u[lane], uv1 = u[64 + lane];
    float wc00 = Wc[lane * 2 + 0], wc01 = Wc[lane * 2 + 1];
    float wc10 = Wc[(lane + 64) * 2 + 0], wc11 = Wc[(lane + 64) * 2 + 1];
    float b0 = bb[0], b1 = bb[1];
    float lsum = 0.f, csum = 0.f;
    for (int w = gw; w < Mtot; w += nw) {
        int node = idx[w];
        float v0 = __bfloat162float(h[(size_t)node * DOUT + lane]);
        float v1 = __bfloat162float(h[(size_t)node * DOUT + 64 + lane]);
        float ps = v0 * uv0 + v1 * uv1;
        float p0 = v0 * wc00 + v1 * wc10;
        float p1 = v0 * wc01 + v1 * wc11;
#pragma unroll
        for (int o = 32; o > 0; o >>= 1) {
            ps += __shfl_xor(ps, o, 64);
            p0 += __shfl_xor(p0, o, 64);
            p1 += __shfl_xor(p1, o, 64);
        }
        if (lane == 0) {
            float y0 = label[(size_t)node * NCLS + 0];
            float y1 = label[(size_t)node * NCLS + 1];
            lsum += softplusf(-(y0 * ps)) + softplusf(-(y1 * ps));
            float l0 = p0 + b0, l1 = p1 + b1;
            int pred = (l1 > l0) ? 1 : 0;
            int truth = (y1 > y0) ? 1 : 0;
            csum += (pred == truth) ? 1.f : 0.f;
        }
    }
    if (lane == 0) { sl[wid] = lsum; sc2[wid] = csum; }
    __syncthreads();
    if (threadIdx.x == 0) {
        blockpart[blockIdx.x * 2 + 0] = sl[0] + sl[1] + sl[2] + sl[3];
        blockpart[blockIdx.x * 2 + 1] = sc2[0] + sc2[1] + sc2[2] + sc2[3];
    }
}

__global__ __launch_bounds__(256) void k_final(const float* __restrict__ bp,
                                               float* __restrict__ out, int nb) {
    __shared__ float sl[256], sc2[256];
    int t = threadIdx.x;
    float l = 0.f, c = 0.f;
    for (int i = t; i < nb; i += 256) { l += bp[i * 2]; c += bp[i * 2 + 1]; }
    sl[t] = l; sc2[t] = c;
    __syncthreads();
    for (int o = 128; o > 0; o >>= 1) {
        if (t < o) { sl[t] += sl[t + o]; sc2[t] += sc2[t + o]; }
        __syncthreads();
    }
    if (t == 0) { out[0] = sl[0]; out[1] = sc2[0] * (1.0f / NMASK); }
}

// ---------------- launch ----------------
extern "C" void kernel_launch(void* const* d_in, const int* in_sizes, int n_in,
                              void* d_out, int out_size, void* d_ws, size_t ws_size,
                              hipStream_t stream) {
    const float* x      = (const float*)d_in[0];
    const float* label  = (const float*)d_in[1];
    const int*   idx    = (const int*)d_in[2];
    const int*   src    = (const int*)d_in[3];
    const int*   dst    = (const int*)d_in[4];
    const float* vals   = (const float*)d_in[5];
    const float* h0     = (const float*)d_in[6];
    const float* Ws     = (const float*)d_in[7];
    const float* Vs     = (const float*)d_in[8];
    const float* alphas = (const float*)d_in[9];
    const float* Wc     = (const float*)d_in[10];
    const float* bb     = (const float*)d_in[11];
    const float* u      = (const float*)d_in[12];
    float* out = (float*)d_out;

    char* p = (char*)d_ws;
    __hip_bfloat16* aggcb = (__hip_bfloat16*)p; p += (size_t)N_NODES * DOUT * 2;  // 12.8 MB
    __hip_bfloat16* xb    = (__hip_bfloat16*)p; p += (size_t)N_NODES * DIN * 2;   // 25.6 MB
    unsigned char*  h8    = (unsigned char*)p;  p += (size_t)N_NODES * DOUT;      // 6.4 MB
    uint2*          edh0  = (uint2*)p;          p += (size_t)TE * 8;              // 12 MB
    uint2*          edh1  = (uint2*)p;          p += (size_t)TE * 8;              // 12 MB
    int*            offs  = (int*)p;            p += 200064 * 4;                  // ~0.8 MB
    __hip_bfloat16* WsT   = (__hip_bfloat16*)p; p += (size_t)NHOP * DOUT * DIN * 2;  // 128 KB
    __hip_bfloat16* VsT   = (__hip_bfloat16*)p; p += (size_t)NHOP * DOUT * DOUT * 2; // 64 KB
    float*          blockpart = (float*)p;      p += LOSS_BLOCKS * 2 * 4;
    // CSR-build scratch aliases xb (xb written by k_cvt AFTER k_bsort; stream-serial)
    uint2* ebkt  = (uint2*)xb;                            // 12 MB
    int*   bh    = (int*)((char*)xb + (size_t)TE * 8);    // 576 KB
    int*   sc    = bh + BHN;                              // 576 KB
    int*   bsums = sc + BHN;
    // hbf (final bf16 h, 12.8 MB) aliases edh1+offs: both dead after hop-2 k_agg,
    // hbf written only by hop-2 k_mm (stream-serial). 12,800,000 <= 12,800,256 B.
    __hip_bfloat16* hbf = (__hip_bfloat16*)edh1;

    // bucket-binned CSR build (per-hop prescaled weights; reused for both hops)
    k_bhist<<<NBLKA, 256, 0, stream>>>(dst, bh);
    k_scanA<<<SCANBLKS, SCT, 0, stream>>>(bh, sc, bsums, BHN);
    k_scanB<<<1, SCT, 0, stream>>>(bsums, SCANBLKS);
    k_scanC<<<SCANBLKS, SCT, 0, stream>>>(sc, bsums, BHN);
    k_bbin<<<NBLKA, 256, 0, stream>>>(src, dst, vals, sc, ebkt);
    k_bsort<<<NBUCK, 256, 0, stream>>>(ebkt, sc, alphas, edh0, edh1, offs);

    // conversions: h0 -> fp8 (first gather), x -> bf16 (GEMM A1), weights transposed
    k_cvt8<<<(N_NODES * DOUT / 4 + 255) / 256, 256, 0, stream>>>(h0, h8, N_NODES * DOUT / 4);
    k_cvt<<<(N_NODES * DIN / 2 + 255) / 256, 256, 0, stream>>>(x, xb, N_NODES * DIN / 2);
    k_tw<<<(NHOP * (DIN * DOUT + DOUT * DOUT) + 255) / 256, 256, 0, stream>>>(Ws, Vs, WsT, VsT);

    const int MMBLK = (N_NODES + 127) / 128;  // 391
    // hop 1: gather h0(fp8) -> agg; h1 = sigmoid(x@W0 + agg@V0) -> fp8 only
    k_agg<<<(N_NODES + 3) / 4, 256, 0, stream>>>(h8, edh0, offs, aggcb);
    k_mm<<<MMBLK, 256, 0, stream>>>(xb, WsT, aggcb, VsT, h8, nullptr, N_NODES, DIN, DOUT);
    // hop 2: gather h1(fp8) -> agg; h2 = sigmoid(x@W1 + agg@V1) -> bf16 (for loss)
    k_agg<<<(N_NODES + 3) / 4, 256, 0, stream>>>(h8, edh1, offs, aggcb);
    k_mm<<<MMBLK, 256, 0, stream>>>(xb, WsT + (size_t)DOUT * DIN, aggcb,
                                    VsT + (size_t)DOUT * DOUT, nullptr, hbf,
                                    N_NODES, DIN, DOUT);

    k_loss<<<LOSS_BLOCKS, 256, 0, stream>>>(hbf, label, idx, u, Wc, bb, blockpart, NMASK);
    k_final<<<1, 256, 0, stream>>>(blockpart, out, LOSS_BLOCKS);
}

// Round 8
// 215.962 us; speedup vs baseline: 4.3601x; 1.1877x over previous
//
#include <hip/hip_runtime.h>
#include <hip/hip_bf16.h>

#define N_NODES 50000
#define DIN     256
#define DOUT    128
#define NCLS    2
#define NHOP    2
#define NDEV    3
#define EDG     500000
#define TE      (NDEV*EDG)
#define NMASK   10000
#define LOSS_BLOCKS 2500             // one masked node per wave

#define BUCK    128
#define NBUCK   391                  // ceil(50000/128)
#define CH      2048                 // edges per binning block
#define NBLKA   733                  // ceil(TE/CH)
#define BHN     (NBUCK*NBLKA)        // 286,603
#define SCT     512
#define SCANBLKS ((BHN + SCT - 1) / SCT)   // 560

typedef __attribute__((ext_vector_type(8))) short bf16x8;   // 8 bf16 = 4 VGPRs
typedef __attribute__((ext_vector_type(4))) float f32x4;
typedef __attribute__((ext_vector_type(2))) float f32x2;

__device__ __forceinline__ float softplusf(float a) {
    return fmaxf(a, 0.f) + log1pf(expf(-fabsf(a)));
}

// fp8 e4m3 (OCP on gfx950) helpers via HW pack/unpack
__device__ __forceinline__ f32x2 fp8lo(unsigned g) {
    return __builtin_amdgcn_cvt_pk_f32_fp8(g, false);
}
__device__ __forceinline__ f32x2 fp8hi(unsigned g) {
    return __builtin_amdgcn_cvt_pk_f32_fp8(g, true);
}
__device__ __forceinline__ unsigned char fp8enc1(float v) {
    return (unsigned char)(__builtin_amdgcn_cvt_pk_fp8_f32(v, v, 0, false) & 0xFF);
}

// ---------------- bucket-binned CSR build (write-amp ~1x) ----------------

__global__ __launch_bounds__(256) void k_bhist(const int* __restrict__ dst,
                                               int* __restrict__ bh) {
    __shared__ int hist[NBUCK];
    int blk = blockIdx.x, tid = threadIdx.x;
    for (int i = tid; i < NBUCK; i += 256) hist[i] = 0;
    __syncthreads();
    int base = blk * CH;
    int lim = min(base + CH, TE);
    for (int i = base + tid; i < lim; i += 256) atomicAdd(&hist[dst[i] >> 7], 1);
    __syncthreads();
    for (int i = tid; i < NBUCK; i += 256) bh[(size_t)i * NBLKA + blk] = hist[i];
}

__global__ __launch_bounds__(SCT) void k_scanA(const int* __restrict__ in,
                                               int* __restrict__ out,
                                               int* __restrict__ bsums, int n) {
    __shared__ int s[SCT];
    int tid = threadIdx.x, gid = blockIdx.x * SCT + tid;
    int v = (gid < n) ? in[gid] : 0;
    s[tid] = v; __syncthreads();
    for (int o = 1; o < SCT; o <<= 1) {
        int t = (tid >= o) ? s[tid - o] : 0;
        __syncthreads();
        s[tid] += t;
        __syncthreads();
    }
    if (gid < n) out[gid] = s[tid] - v;          // exclusive
    if (tid == SCT - 1) bsums[blockIdx.x] = s[SCT - 1];
}

// single-block carry-looped exclusive scan (handles nb > SCT)
__global__ __launch_bounds__(SCT) void k_scanB(int* __restrict__ bsums, int nb) {
    __shared__ int s[SCT];
    int tid = threadIdx.x;
    int carry = 0;
    for (int base = 0; base < nb; base += SCT) {
        int v = (base + tid < nb) ? bsums[base + tid] : 0;
        s[tid] = v; __syncthreads();
        for (int o = 1; o < SCT; o <<= 1) {
            int t = (tid >= o) ? s[tid - o] : 0;
            __syncthreads();
            s[tid] += t;
            __syncthreads();
        }
        if (base + tid < nb) bsums[base + tid] = s[tid] - v + carry;
        carry += s[SCT - 1];
        __syncthreads();
    }
}

__global__ __launch_bounds__(SCT) void k_scanC(int* __restrict__ out,
                                               const int* __restrict__ bsums, int n) {
    int gid = blockIdx.x * SCT + threadIdx.x;
    if (gid < n) out[gid] += bsums[blockIdx.x];
}

// bin edges into bucket-grouped array; pack src(16) | dev(2)<<16 | dstlocal(7)<<18
__global__ __launch_bounds__(256) void k_bbin(const int* __restrict__ src,
                                              const int* __restrict__ dst,
                                              const float* __restrict__ vals,
                                              const int* __restrict__ sc,
                                              uint2* __restrict__ ebkt) {
    __shared__ int cur[NBUCK];
    int blk = blockIdx.x, tid = threadIdx.x;
    for (int i = tid; i < NBUCK; i += 256) cur[i] = sc[(size_t)i * NBLKA + blk];
    __syncthreads();
    int base = blk * CH;
    int lim = min(base + CH, TE);
    for (int i = base + tid; i < lim; i += 256) {
        int d = i / EDG;
        int n = dst[i];
        int bu = n >> 7;
        int pos = atomicAdd(&cur[bu], 1);
        ebkt[pos] = make_uint2((unsigned)src[i] | ((unsigned)d << 16) |
                               ((unsigned)(n & 127) << 18),
                               __float_as_uint(vals[i]));
    }
}

// per-bucket counting sort by node; emits per-hop {src, alpha*val} arrays + offsets
__global__ __launch_bounds__(256) void k_bsort(const uint2* __restrict__ ebkt,
                                               const int* __restrict__ sc,
                                               const float* __restrict__ alphas,
                                               uint2* __restrict__ edh0,
                                               uint2* __restrict__ edh1,
                                               int* __restrict__ offs) {
    __shared__ int cnt[BUCK], start[BUCK + 1], cur[BUCK];
    int b = blockIdx.x, tid = threadIdx.x;
    float a00 = alphas[0], a01 = alphas[1], a02 = alphas[2];
    float a10 = alphas[3], a11 = alphas[4], a12 = alphas[5];
    int beg = sc[(size_t)b * NBLKA];
    int end = (b + 1 < NBUCK) ? sc[(size_t)(b + 1) * NBLKA] : TE;
    if (tid < BUCK) { cnt[tid] = 0; cur[tid] = 0; }
    __syncthreads();
    for (int e = beg + tid; e < end; e += 256)
        atomicAdd(&cnt[(ebkt[e].x >> 18) & 127], 1);
    __syncthreads();
    if (tid == 0) {
        int acc = 0;
        for (int i = 0; i < BUCK; ++i) { start[i] = acc; acc += cnt[i]; }
        start[BUCK] = acc;
    }
    __syncthreads();
    if (tid < BUCK) {
        int n = b * BUCK + tid;
        if (n < N_NODES) offs[n] = beg + start[tid];
    }
    if (b == 0 && tid == 255) offs[N_NODES] = TE;
    for (int e = beg + tid; e < end; e += 256) {
        uint2 v = ebkt[e];
        int dl = (v.x >> 18) & 127;
        int pos = beg + start[dl] + atomicAdd(&cur[dl], 1);
        unsigned s = v.x & 0xFFFFu;
        int d = (v.x >> 16) & 3;
        float val = __uint_as_float(v.y);
        float w0 = val * (d == 0 ? a00 : (d == 1 ? a01 : a02));
        float w1 = val * (d == 0 ? a10 : (d == 1 ? a11 : a12));
        edh0[pos] = make_uint2(s, __float_as_uint(w0));
        edh1[pos] = make_uint2(s, __float_as_uint(w1));
    }
}

// fp32 -> bf16 copy (float2 per thread)
__global__ void k_cvt(const float* __restrict__ in, __hip_bfloat16* __restrict__ out, int n2) {
    int i = blockIdx.x * blockDim.x + threadIdx.x;
    if (i >= n2) return;
    float2 f = ((const float2*)in)[i];
    __hip_bfloat162 b;
    b.x = __float2bfloat16(f.x);
    b.y = __float2bfloat16(f.y);
    ((__hip_bfloat162*)out)[i] = b;
}

// fp32 -> fp8 e4m3 copy (float4 -> 4 bytes per thread)
__global__ void k_cvt8(const float* __restrict__ in, unsigned char* __restrict__ out, int n4) {
    int i = blockIdx.x * blockDim.x + threadIdx.x;
    if (i >= n4) return;
    float4 f = ((const float4*)in)[i];
    int r = 0;
    r = __builtin_amdgcn_cvt_pk_fp8_f32(f.x, f.y, r, false);
    r = __builtin_amdgcn_cvt_pk_fp8_f32(f.z, f.w, r, true);
    ((unsigned*)out)[i] = (unsigned)r;
}

// weight transpose+convert: WsT[hop][n][k] = bf16(Ws[hop][k][n]); same for Vs
__global__ void k_tw(const float* __restrict__ Ws, const float* __restrict__ Vs,
                     __hip_bfloat16* __restrict__ WsT, __hip_bfloat16* __restrict__ VsT) {
    int i = blockIdx.x * 256 + threadIdx.x;
    if (i < NHOP * DIN * DOUT) {
        int hop = i / (DIN * DOUT);
        int r = i % (DIN * DOUT);
        int k = r >> 7, n = r & 127;
        WsT[(size_t)hop * DOUT * DIN + (size_t)n * DIN + k] = __float2bfloat16(Ws[i]);
    } else {
        int j = i - NHOP * DIN * DOUT;
        if (j < NHOP * DOUT * DOUT) {
            int hop = j / (DOUT * DOUT);
            int r = j % (DOUT * DOUT);
            int k = r >> 7, n = r & 127;
            VsT[(size_t)hop * DOUT * DOUT + (size_t)n * DOUT + k] = __float2bfloat16(Vs[j]);
        }
    }
}

// ---------------- sparse aggregation: one wave per node, fp8 rows, 2 edges/wave ------
__global__ __launch_bounds__(256) void k_agg(const unsigned char* __restrict__ h8,
                                             const uint2* __restrict__ edh,
                                             const int* __restrict__ offs,
                                             __hip_bfloat16* __restrict__ aggcb) {
    int wid = threadIdx.x >> 6;
    int lane = threadIdx.x & 63;
    int n = blockIdx.x * 4 + wid;
    if (n >= N_NODES) return;
    int half = lane >> 5;        // 0 = even edge, 1 = odd edge
    int c4 = lane & 31;          // 4-byte chunk of the 128B fp8 row
    int beg = offs[n], end = offs[n + 1];
    float a0 = 0.f, a1 = 0.f, a2 = 0.f, a3 = 0.f;
    int e = beg;
    for (; e + 8 <= end; e += 8) {
#pragma unroll
        for (int p = 0; p < 4; ++p) {
            uint2 q = edh[e + p * 2 + half];           // {src, w}
            unsigned g = *(const unsigned*)(h8 + (size_t)q.x * DOUT + c4 * 4);
            float wt = __uint_as_float(q.y);
            f32x2 lo = fp8lo(g), hi = fp8hi(g);
            a0 += wt * lo[0]; a1 += wt * lo[1];
            a2 += wt * hi[0]; a3 += wt * hi[1];
        }
    }
    for (; e + 2 <= end; e += 2) {
        uint2 q = edh[e + half];
        unsigned g = *(const unsigned*)(h8 + (size_t)q.x * DOUT + c4 * 4);
        float wt = __uint_as_float(q.y);
        f32x2 lo = fp8lo(g), hi = fp8hi(g);
        a0 += wt * lo[0]; a1 += wt * lo[1];
        a2 += wt * hi[0]; a3 += wt * hi[1];
    }
    if (e < end && half == 0) {                        // odd-degree tail
        uint2 q = edh[e];
        unsigned g = *(const unsigned*)(h8 + (size_t)q.x * DOUT + c4 * 4);
        float wt = __uint_as_float(q.y);
        f32x2 lo = fp8lo(g), hi = fp8hi(g);
        a0 += wt * lo[0]; a1 += wt * lo[1];
        a2 += wt * hi[0]; a3 += wt * hi[1];
    }
    a0 += __shfl_xor(a0, 32, 64);
    a1 += __shfl_xor(a1, 32, 64);
    a2 += __shfl_xor(a2, 32, 64);
    a3 += __shfl_xor(a3, 32, 64);
    if (half == 0) {
        union { __hip_bfloat16 h[4]; ushort4 u; } pk;
        pk.h[0] = __float2bfloat16(a0);
        pk.h[1] = __float2bfloat16(a1);
        pk.h[2] = __float2bfloat16(a2);
        pk.h[3] = __float2bfloat16(a3);
        *(ushort4*)(aggcb + (size_t)n * DOUT + c4 * 4) = pk.u;
    }
}

// ---------------- fused MFMA GEMM: h = sigmoid(A1@B1 + A2@B2), bf16 in --------------
__global__ __launch_bounds__(256) void k_mm(const __hip_bfloat16* __restrict__ A1,
                                            const __hip_bfloat16* __restrict__ BT1,
                                            const __hip_bfloat16* __restrict__ A2,
                                            const __hip_bfloat16* __restrict__ BT2,
                                            unsigned char* __restrict__ C8,
                                            __hip_bfloat16* __restrict__ Cbf,
                                            int M, int K1, int K2) {
    __shared__ short As[128][40];   // stride 40: bank-starts spread 8-periodic
    __shared__ short Bs[128][40];
    int tid = threadIdx.x;
    int lane = tid & 63;
    int w = tid >> 6;
    int wr = (w >> 1) * 64, wc = (w & 1) * 64;
    int lr = lane & 15, kg = lane >> 4;
    int row0 = blockIdx.x * 128;

    f32x4 acc[4][4];
#pragma unroll
    for (int mi = 0; mi < 4; ++mi)
#pragma unroll
        for (int ni = 0; ni < 4; ++ni) acc[mi][ni] = (f32x4){0.f, 0.f, 0.f, 0.f};

#pragma unroll
    for (int seg = 0; seg < 2; ++seg) {
        const __hip_bfloat16* A = seg ? A2 : A1;
        const __hip_bfloat16* BT = seg ? BT2 : BT1;
        int K = seg ? K2 : K1;
        for (int k0 = 0; k0 < K; k0 += 32) {
#pragma unroll
            for (int j = 0; j < 2; ++j) {           // stage A tile: 512 x 16B chunks
                int c = tid + j * 256;
                int r = c >> 2, kc = (c & 3) * 8;
                bf16x8 g = {};
                int gr = row0 + r;
                if (gr < M) g = *(const bf16x8*)(A + (size_t)gr * K + k0 + kc);
                *(bf16x8*)&As[r][kc] = g;
            }
#pragma unroll
            for (int j = 0; j < 2; ++j) {           // stage BT tile
                int c = tid + j * 256;
                int r = c >> 2, kc = (c & 3) * 8;
                *(bf16x8*)&Bs[r][kc] = *(const bf16x8*)(BT + (size_t)r * K + k0 + kc);
            }
            __syncthreads();
            bf16x8 af[4], bfr[4];
#pragma unroll
            for (int i = 0; i < 4; ++i) {
                af[i]  = *(const bf16x8*)&As[wr + i * 16 + lr][kg * 8];
                bfr[i] = *(const bf16x8*)&Bs[wc + i * 16 + lr][kg * 8];
            }
#pragma unroll
            for (int mi = 0; mi < 4; ++mi)
#pragma unroll
                for (int ni = 0; ni < 4; ++ni)
                    acc[mi][ni] = __builtin_amdgcn_mfma_f32_16x16x32_bf16(
                        af[mi], bfr[ni], acc[mi][ni], 0, 0, 0);
            __syncthreads();
        }
    }

#pragma unroll
    for (int mi = 0; mi < 4; ++mi) {
#pragma unroll
        for (int r = 0; r < 4; ++r) {
            int row = row0 + wr + mi * 16 + kg * 4 + r;   // C/D: row=(lane>>4)*4+reg
            if (row < M) {
#pragma unroll
                for (int ni = 0; ni < 4; ++ni) {
                    int col = wc + ni * 16 + lr;          // C/D: col=lane&15
                    float v = acc[mi][ni][r];
                    v = 1.f / (1.f + __expf(-v));
                    if (C8)  C8[(size_t)row * DOUT + col] = fp8enc1(v);
                    if (Cbf) Cbf[(size_t)row * DOUT + col] = __float2bfloat16(v);
                }
            }
        }
    }
}

// ---------------- masked loss + accuracy: one node per wave ----------------
__global__ __launch_bounds__(256) void k_loss(const __hip_bfloat16* __restrict__ h,
                                              const float* __restrict__ label,
                                              const int* __restrict__ idx,
                                              const float* __restrict__ u,
                                              const float* __restrict__ Wc,
                                              const float* __restrict__ bb,
                                              float* __restrict__ blockpart, int Mtot) {
    __shared__ float sl[4], sc2[4];
    int wid = threadIdx.x >> 6;
    int lane = threadIdx.x & 63;
    int w = blockIdx.x * 4 + wid;
    float lsum = 0.f, csum = 0.f;
    if (w < Mtot) {
        int node = idx[w];
        float v0 = __bfloat162float(h[(size_t)node * DOUT + lane]);
        float v1 = __bfloat162float(h[(size_t)node * DOUT + 64 + lane]);
        float ps = v0 * u[lane] + v1 * u[64 + lane];
        float p0 = v0 * Wc[lane * 2 + 0] + v1 * Wc[(lane + 64) * 2 + 0];
        float p1 = v0 * Wc[lane * 2 + 1] + v1 * Wc[(lane + 64) * 2 + 1];
#pragma unroll
        for (int o = 32; o > 0; o >>= 1) {
            ps += __shfl_xor(ps, o, 64);
            p0 += __shfl_xor(p0, o, 64);
            p1 += __shfl_xor(p1, o, 64);
        }
        if (lane == 0) {
            float y0 = label[(size_t)node * NCLS + 0];
            float y1 = label[(size_t)node * NCLS + 1];
            lsum = softplusf(-(y0 * ps)) + softplusf(-(y1 * ps));
            float l0 = p0 + bb[0], l1 = p1 + bb[1];
            int pred = (l1 > l0) ? 1 : 0;
            int truth = (y1 > y0) ? 1 : 0;
            csum = (pred == truth) ? 1.f : 0.f;
        }
    }
    if (lane == 0) { sl[wid] = lsum; sc2[wid] = csum; }
    __syncthreads();
    if (threadIdx.x == 0) {
        blockpart[blockIdx.x * 2 + 0] = sl[0] + sl[1] + sl[2] + sl[3];
        blockpart[blockIdx.x * 2 + 1] = sc2[0] + sc2[1] + sc2[2] + sc2[3];
    }
}

__global__ __launch_bounds__(256) void k_final(const float* __restrict__ bp,
                                               float* __restrict__ out, int nb) {
    __shared__ float sl[256], sc2[256];
    int t = threadIdx.x;
    float l = 0.f, c = 0.f;
    for (int i = t; i < nb; i += 256) { l += bp[i * 2]; c += bp[i * 2 + 1]; }
    sl[t] = l; sc2[t] = c;
    __syncthreads();
    for (int o = 128; o > 0; o >>= 1) {
        if (t < o) { sl[t] += sl[t + o]; sc2[t] += sc2[t + o]; }
        __syncthreads();
    }
    if (t == 0) { out[0] = sl[0]; out[1] = sc2[0] * (1.0f / NMASK); }
}

// ---------------- launch ----------------
extern "C" void kernel_launch(void* const* d_in, const int* in_sizes, int n_in,
                              void* d_out, int out_size, void* d_ws, size_t ws_size,
                              hipStream_t stream) {
    const float* x      = (const float*)d_in[0];
    const float* label  = (const float*)d_in[1];
    const int*   idx    = (const int*)d_in[2];
    const int*   src    = (const int*)d_in[3];
    const int*   dst    = (const int*)d_in[4];
    const float* vals   = (const float*)d_in[5];
    const float* h0     = (const float*)d_in[6];
    const float* Ws     = (const float*)d_in[7];
    const float* Vs     = (const float*)d_in[8];
    const float* alphas = (const float*)d_in[9];
    const float* Wc     = (const float*)d_in[10];
    const float* bb     = (const float*)d_in[11];
    const float* u      = (const float*)d_in[12];
    float* out = (float*)d_out;

    char* p = (char*)d_ws;
    __hip_bfloat16* aggcb = (__hip_bfloat16*)p; p += (size_t)N_NODES * DOUT * 2;  // 12.8 MB
    __hip_bfloat16* xb    = (__hip_bfloat16*)p; p += (size_t)N_NODES * DIN * 2;   // 25.6 MB
    unsigned char*  h8    = (unsigned char*)p;  p += (size_t)N_NODES * DOUT;      // 6.4 MB
    uint2*          edh0  = (uint2*)p;          p += (size_t)TE * 8;              // 12 MB
    uint2*          edh1  = (uint2*)p;          p += (size_t)TE * 8;              // 12 MB
    int*            offs  = (int*)p;            p += 200064 * 4;                  // ~0.8 MB
    __hip_bfloat16* WsT   = (__hip_bfloat16*)p; p += (size_t)NHOP * DOUT * DIN * 2;  // 128 KB
    __hip_bfloat16* VsT   = (__hip_bfloat16*)p; p += (size_t)NHOP * DOUT * DOUT * 2; // 64 KB
    float*          blockpart = (float*)p;      p += LOSS_BLOCKS * 2 * 4;         // 20 KB
    // CSR-build scratch aliases xb (xb written by k_cvt AFTER k_bsort; stream-serial)
    uint2* ebkt  = (uint2*)xb;                            // 12 MB
    int*   bh    = (int*)((char*)xb + (size_t)TE * 8);    // 1.15 MB
    int*   sc    = bh + BHN;                              // 1.15 MB
    int*   bsums = sc + BHN;
    // hbf (final bf16 h, 12.8 MB) aliases edh1+offs (dead after hop-2 k_agg)
    __hip_bfloat16* hbf = (__hip_bfloat16*)edh1;

    // bucket-binned CSR build (per-hop prescaled weights; reused for both hops)
    k_bhist<<<NBLKA, 256, 0, stream>>>(dst, bh);
    k_scanA<<<SCANBLKS, SCT, 0, stream>>>(bh, sc, bsums, BHN);
    k_scanB<<<1, SCT, 0, stream>>>(bsums, SCANBLKS);
    k_scanC<<<SCANBLKS, SCT, 0, stream>>>(sc, bsums, BHN);
    k_bbin<<<NBLKA, 256, 0, stream>>>(src, dst, vals, sc, ebkt);
    k_bsort<<<NBUCK, 256, 0, stream>>>(ebkt, sc, alphas, edh0, edh1, offs);

    // conversions: h0 -> fp8 (first gather), x -> bf16 (GEMM A1), weights transposed
    k_cvt8<<<(N_NODES * DOUT / 4 + 255) / 256, 256, 0, stream>>>(h0, h8, N_NODES * DOUT / 4);
    k_cvt<<<(N_NODES * DIN / 2 + 255) / 256, 256, 0, stream>>>(x, xb, N_NODES * DIN / 2);
    k_tw<<<(NHOP * (DIN * DOUT + DOUT * DOUT) + 255) / 256, 256, 0, stream>>>(Ws, Vs, WsT, VsT);

    const int MMBLK = (N_NODES + 127) / 128;  // 391
    // hop 1: gather h0(fp8) -> agg; h1 = sigmoid(x@W0 + agg@V0) -> fp8 only
    k_agg<<<(N_NODES + 3) / 4, 256, 0, stream>>>(h8, edh0, offs, aggcb);
    k_mm<<<MMBLK, 256, 0, stream>>>(xb, WsT, aggcb, VsT, h8, nullptr, N_NODES, DIN, DOUT);
    // hop 2: gather h1(fp8) -> agg; h2 = sigmoid(x@W1 + agg@V1) -> bf16 (for loss)
    k_agg<<<(N_NODES + 3) / 4, 256, 0, stream>>>(h8, edh1, offs, aggcb);
    k_mm<<<MMBLK, 256, 0, stream>>>(xb, WsT + (size_t)DOUT * DIN, aggcb,
                                    VsT + (size_t)DOUT * DOUT, nullptr, hbf,
                                    N_NODES, DIN, DOUT);

    k_loss<<<LOSS_BLOCKS, 256, 0, stream>>>(hbf, label, idx, u, Wc, bb, blockpart, NMASK);
    k_final<<<1, 256, 0, stream>>>(blockpart, out, LOSS_BLOCKS);
}

// Round 9
// 207.000 us; speedup vs baseline: 4.5489x; 1.0433x over previous
//
#include <hip/hip_runtime.h>
#include <hip/hip_bf16.h>

#define N_NODES 50000
#define DIN     256
#define DOUT    128
#define NCLS    2
#define NHOP    2
#define NDEV    3
#define EDG     500000
#define TE      (NDEV*EDG)
#define NMASK   10000
#define LOSS_BLOCKS 2500             // one masked node per wave

#define BUCK    128
#define NBUCK   391                  // ceil(50000/128)
#define CH      2048                 // edges per binning block
#define NBLKA   733                  // ceil(TE/CH)
#define BHN     (NBUCK*NBLKA)        // 286,603
#define SCT     512
#define SCANBLKS ((BHN + SCT - 1) / SCT)   // 560

typedef __attribute__((ext_vector_type(8))) short bf16x8;   // 8 bf16 = 4 VGPRs
typedef __attribute__((ext_vector_type(4))) float f32x4;
typedef __attribute__((ext_vector_type(2))) float f32x2;

__device__ __forceinline__ float softplusf(float a) {
    return fmaxf(a, 0.f) + log1pf(expf(-fabsf(a)));
}

// fp8 e4m3 (OCP on gfx950) helpers via HW pack/unpack
__device__ __forceinline__ f32x2 fp8lo(unsigned g) {
    return __builtin_amdgcn_cvt_pk_f32_fp8(g, false);
}
__device__ __forceinline__ f32x2 fp8hi(unsigned g) {
    return __builtin_amdgcn_cvt_pk_f32_fp8(g, true);
}
__device__ __forceinline__ unsigned char fp8enc1(float v) {
    return (unsigned char)(__builtin_amdgcn_cvt_pk_fp8_f32(v, v, 0, false) & 0xFF);
}

// ---------------- bucket-binned CSR build (write-amp ~1x) ----------------

__global__ __launch_bounds__(256) void k_bhist(const int* __restrict__ dst,
                                               int* __restrict__ bh) {
    __shared__ int hist[NBUCK];
    int blk = blockIdx.x, tid = threadIdx.x;
    for (int i = tid; i < NBUCK; i += 256) hist[i] = 0;
    __syncthreads();
    int base = blk * CH;
    int lim = min(base + CH, TE);
    for (int i = base + tid; i < lim; i += 256) atomicAdd(&hist[dst[i] >> 7], 1);
    __syncthreads();
    for (int i = tid; i < NBUCK; i += 256) bh[(size_t)i * NBLKA + blk] = hist[i];
}

__global__ __launch_bounds__(SCT) void k_scanA(const int* __restrict__ in,
                                               int* __restrict__ out,
                                               int* __restrict__ bsums, int n) {
    __shared__ int s[SCT];
    int tid = threadIdx.x, gid = blockIdx.x * SCT + tid;
    int v = (gid < n) ? in[gid] : 0;
    s[tid] = v; __syncthreads();
    for (int o = 1; o < SCT; o <<= 1) {
        int t = (tid >= o) ? s[tid - o] : 0;
        __syncthreads();
        s[tid] += t;
        __syncthreads();
    }
    if (gid < n) out[gid] = s[tid] - v;          // exclusive
    if (tid == SCT - 1) bsums[blockIdx.x] = s[SCT - 1];
}

// single-block carry-looped exclusive scan (handles nb > SCT)
__global__ __launch_bounds__(SCT) void k_scanB(int* __restrict__ bsums, int nb) {
    __shared__ int s[SCT];
    int tid = threadIdx.x;
    int carry = 0;
    for (int base = 0; base < nb; base += SCT) {
        int v = (base + tid < nb) ? bsums[base + tid] : 0;
        s[tid] = v; __syncthreads();
        for (int o = 1; o < SCT; o <<= 1) {
            int t = (tid >= o) ? s[tid - o] : 0;
            __syncthreads();
            s[tid] += t;
            __syncthreads();
        }
        if (base + tid < nb) bsums[base + tid] = s[tid] - v + carry;
        carry += s[SCT - 1];
        __syncthreads();
    }
}

__global__ __launch_bounds__(SCT) void k_scanC(int* __restrict__ out,
                                               const int* __restrict__ bsums, int n) {
    int gid = blockIdx.x * SCT + threadIdx.x;
    if (gid < n) out[gid] += bsums[blockIdx.x];
}

// bin edges into bucket-grouped array; pack src(16) | dev(2)<<16 | dstlocal(7)<<18
__global__ __launch_bounds__(256) void k_bbin(const int* __restrict__ src,
                                              const int* __restrict__ dst,
                                              const float* __restrict__ vals,
                                              const int* __restrict__ sc,
                                              uint2* __restrict__ ebkt) {
    __shared__ int cur[NBUCK];
    int blk = blockIdx.x, tid = threadIdx.x;
    for (int i = tid; i < NBUCK; i += 256) cur[i] = sc[(size_t)i * NBLKA + blk];
    __syncthreads();
    int base = blk * CH;
    int lim = min(base + CH, TE);
    for (int i = base + tid; i < lim; i += 256) {
        int d = i / EDG;
        int n = dst[i];
        int bu = n >> 7;
        int pos = atomicAdd(&cur[bu], 1);
        ebkt[pos] = make_uint2((unsigned)src[i] | ((unsigned)d << 16) |
                               ((unsigned)(n & 127) << 18),
                               __float_as_uint(vals[i]));
    }
}

// per-bucket counting sort by node; emits per-hop {src, alpha*val} arrays + offsets
__global__ __launch_bounds__(256) void k_bsort(const uint2* __restrict__ ebkt,
                                               const int* __restrict__ sc,
                                               const float* __restrict__ alphas,
                                               uint2* __restrict__ edh0,
                                               uint2* __restrict__ edh1,
                                               int* __restrict__ offs) {
    __shared__ int cnt[BUCK], start[BUCK + 1], cur[BUCK];
    int b = blockIdx.x, tid = threadIdx.x;
    float a00 = alphas[0], a01 = alphas[1], a02 = alphas[2];
    float a10 = alphas[3], a11 = alphas[4], a12 = alphas[5];
    int beg = sc[(size_t)b * NBLKA];
    int end = (b + 1 < NBUCK) ? sc[(size_t)(b + 1) * NBLKA] : TE;
    if (tid < BUCK) { cnt[tid] = 0; cur[tid] = 0; }
    __syncthreads();
    for (int e = beg + tid; e < end; e += 256)
        atomicAdd(&cnt[(ebkt[e].x >> 18) & 127], 1);
    __syncthreads();
    if (tid == 0) {
        int acc = 0;
        for (int i = 0; i < BUCK; ++i) { start[i] = acc; acc += cnt[i]; }
        start[BUCK] = acc;
    }
    __syncthreads();
    if (tid < BUCK) {
        int n = b * BUCK + tid;
        if (n < N_NODES) offs[n] = beg + start[tid];
    }
    if (b == 0 && tid == 255) offs[N_NODES] = TE;
    for (int e = beg + tid; e < end; e += 256) {
        uint2 v = ebkt[e];
        int dl = (v.x >> 18) & 127;
        int pos = beg + start[dl] + atomicAdd(&cur[dl], 1);
        unsigned s = v.x & 0xFFFFu;
        int d = (v.x >> 16) & 3;
        float val = __uint_as_float(v.y);
        float w0 = val * (d == 0 ? a00 : (d == 1 ? a01 : a02));
        float w1 = val * (d == 0 ? a10 : (d == 1 ? a11 : a12));
        edh0[pos] = make_uint2(s, __float_as_uint(w0));
        edh1[pos] = make_uint2(s, __float_as_uint(w1));
    }
}

// fp32 -> bf16 copy (float2 per thread)
__global__ void k_cvt(const float* __restrict__ in, __hip_bfloat16* __restrict__ out, int n2) {
    int i = blockIdx.x * blockDim.x + threadIdx.x;
    if (i >= n2) return;
    float2 f = ((const float2*)in)[i];
    __hip_bfloat162 b;
    b.x = __float2bfloat16(f.x);
    b.y = __float2bfloat16(f.y);
    ((__hip_bfloat162*)out)[i] = b;
}

// fp32 -> fp8 e4m3 copy (float4 -> 4 bytes per thread)
__global__ void k_cvt8(const float* __restrict__ in, unsigned char* __restrict__ out, int n4) {
    int i = blockIdx.x * blockDim.x + threadIdx.x;
    if (i >= n4) return;
    float4 f = ((const float4*)in)[i];
    int r = 0;
    r = __builtin_amdgcn_cvt_pk_fp8_f32(f.x, f.y, r, false);
    r = __builtin_amdgcn_cvt_pk_fp8_f32(f.z, f.w, r, true);
    ((unsigned*)out)[i] = (unsigned)r;
}

// weight transpose+convert: WsT[hop][n][k] = bf16(Ws[hop][k][n]); same for Vs
__global__ void k_tw(const float* __restrict__ Ws, const float* __restrict__ Vs,
                     __hip_bfloat16* __restrict__ WsT, __hip_bfloat16* __restrict__ VsT) {
    int i = blockIdx.x * 256 + threadIdx.x;
    if (i < NHOP * DIN * DOUT) {
        int hop = i / (DIN * DOUT);
        int r = i % (DIN * DOUT);
        int k = r >> 7, n = r & 127;
        WsT[(size_t)hop * DOUT * DIN + (size_t)n * DIN + k] = __float2bfloat16(Ws[i]);
    } else {
        int j = i - NHOP * DIN * DOUT;
        if (j < NHOP * DOUT * DOUT) {
            int hop = j / (DOUT * DOUT);
            int r = j % (DOUT * DOUT);
            int k = r >> 7, n = r & 127;
            VsT[(size_t)hop * DOUT * DOUT + (size_t)n * DOUT + k] = __float2bfloat16(Vs[j]);
        }
    }
}

// ---------------- sparse aggregation: one wave per node, 8 edges/iter --------------
// lane = grp(0..7)*8 + cw(0..7): group grp owns edge slot grp; lane loads 16B (16 fp8)
// of that edge's row at byte offset cw*16. 3-level shfl reduction folds the 8 groups.
__global__ __launch_bounds__(256) void k_agg(const unsigned char* __restrict__ h8,
                                             const uint2* __restrict__ edh,
                                             const int* __restrict__ offs,
                                             __hip_bfloat16* __restrict__ aggcb) {
    int wid = threadIdx.x >> 6;
    int lane = threadIdx.x & 63;
    int n = blockIdx.x * 4 + wid;
    if (n >= N_NODES) return;
    int grp = lane >> 3;         // edge slot within the 8-edge batch
    int cw = lane & 7;           // 16-byte chunk of the 128B fp8 row
    int beg = offs[n], end = offs[n + 1];
    float a[16];
#pragma unroll
    for (int j = 0; j < 16; ++j) a[j] = 0.f;

    for (int e = beg; e < end; e += 8) {
        int rem = end - e;
        int ee = e + (grp < rem ? grp : 0);
        uint2 q = edh[ee];                                   // {src, w} (8-lane broadcast)
        float wt = (grp < rem) ? __uint_as_float(q.y) : 0.f;
        uint4 g = *(const uint4*)(h8 + (size_t)q.x * DOUT + cw * 16);
#pragma unroll
        for (int wv = 0; wv < 4; ++wv) {
            unsigned gw = (&g.x)[wv];
            f32x2 lo = fp8lo(gw), hi = fp8hi(gw);
            a[wv * 4 + 0] += wt * lo[0];
            a[wv * 4 + 1] += wt * lo[1];
            a[wv * 4 + 2] += wt * hi[0];
            a[wv * 4 + 3] += wt * hi[1];
        }
    }
    // fold the 8 edge-groups (lane bits 3,4,5)
#pragma unroll
    for (int j = 0; j < 16; ++j) {
        a[j] += __shfl_xor(a[j], 8, 64);
        a[j] += __shfl_xor(a[j], 16, 64);
        a[j] += __shfl_xor(a[j], 32, 64);
    }
    if (grp == 0) {               // lanes 0..7 write cols cw*16 .. cw*16+15
        union { __hip_bfloat16 h[8]; uint4 u; } pk0, pk1;
#pragma unroll
        for (int j = 0; j < 8; ++j) {
            pk0.h[j] = __float2bfloat16(a[j]);
            pk1.h[j] = __float2bfloat16(a[8 + j]);
        }
        *(uint4*)(aggcb + (size_t)n * DOUT + cw * 16) = pk0.u;
        *(uint4*)(aggcb + (size_t)n * DOUT + cw * 16 + 8) = pk1.u;
    }
}

// ---------------- fused MFMA GEMM: h = sigmoid(A1@B1 + A2@B2), bf16 in --------------
__global__ __launch_bounds__(256) void k_mm(const __hip_bfloat16* __restrict__ A1,
                                            const __hip_bfloat16* __restrict__ BT1,
                                            const __hip_bfloat16* __restrict__ A2,
                                            const __hip_bfloat16* __restrict__ BT2,
                                            unsigned char* __restrict__ C8,
                                            __hip_bfloat16* __restrict__ Cbf,
                                            int M, int K1, int K2) {
    __shared__ short As[128][40];   // stride 40: bank-starts spread 8-periodic
    __shared__ short Bs[128][40];
    int tid = threadIdx.x;
    int lane = tid & 63;
    int w = tid >> 6;
    int wr = (w >> 1) * 64, wc = (w & 1) * 64;
    int lr = lane & 15, kg = lane >> 4;
    int row0 = blockIdx.x * 128;

    f32x4 acc[4][4];
#pragma unroll
    for (int mi = 0; mi < 4; ++mi)
#pragma unroll
        for (int ni = 0; ni < 4; ++ni) acc[mi][ni] = (f32x4){0.f, 0.f, 0.f, 0.f};

#pragma unroll
    for (int seg = 0; seg < 2; ++seg) {
        const __hip_bfloat16* A = seg ? A2 : A1;
        const __hip_bfloat16* BT = seg ? BT2 : BT1;
        int K = seg ? K2 : K1;
        for (int k0 = 0; k0 < K; k0 += 32) {
#pragma unroll
            for (int j = 0; j < 2; ++j) {           // stage A tile: 512 x 16B chunks
                int c = tid + j * 256;
                int r = c >> 2, kc = (c & 3) * 8;
                bf16x8 g = {};
                int gr = row0 + r;
                if (gr < M) g = *(const bf16x8*)(A + (size_t)gr * K + k0 + kc);
                *(bf16x8*)&As[r][kc] = g;
            }
#pragma unroll
            for (int j = 0; j < 2; ++j) {           // stage BT tile
                int c = tid + j * 256;
                int r = c >> 2, kc = (c & 3) * 8;
                *(bf16x8*)&Bs[r][kc] = *(const bf16x8*)(BT + (size_t)r * K + k0 + kc);
            }
            __syncthreads();
            bf16x8 af[4], bfr[4];
#pragma unroll
            for (int i = 0; i < 4; ++i) {
                af[i]  = *(const bf16x8*)&As[wr + i * 16 + lr][kg * 8];
                bfr[i] = *(const bf16x8*)&Bs[wc + i * 16 + lr][kg * 8];
            }
#pragma unroll
            for (int mi = 0; mi < 4; ++mi)
#pragma unroll
                for (int ni = 0; ni < 4; ++ni)
                    acc[mi][ni] = __builtin_amdgcn_mfma_f32_16x16x32_bf16(
                        af[mi], bfr[ni], acc[mi][ni], 0, 0, 0);
            __syncthreads();
        }
    }

#pragma unroll
    for (int mi = 0; mi < 4; ++mi) {
#pragma unroll
        for (int r = 0; r < 4; ++r) {
            int row = row0 + wr + mi * 16 + kg * 4 + r;   // C/D: row=(lane>>4)*4+reg
            if (row < M) {
#pragma unroll
                for (int ni = 0; ni < 4; ++ni) {
                    int col = wc + ni * 16 + lr;          // C/D: col=lane&15
                    float v = acc[mi][ni][r];
                    v = 1.f / (1.f + __expf(-v));
                    if (C8)  C8[(size_t)row * DOUT + col] = fp8enc1(v);
                    if (Cbf) Cbf[(size_t)row * DOUT + col] = __float2bfloat16(v);
                }
            }
        }
    }
}

// ---------------- masked loss + accuracy: one node per wave ----------------
__global__ __launch_bounds__(256) void k_loss(const __hip_bfloat16* __restrict__ h,
                                              const float* __restrict__ label,
                                              const int* __restrict__ idx,
                                              const float* __restrict__ u,
                                              const float* __restrict__ Wc,
                                              const float* __restrict__ bb,
                                              float* __restrict__ blockpart, int Mtot) {
    __shared__ float sl[4], sc2[4];
    int wid = threadIdx.x >> 6;
    int lane = threadIdx.x & 63;
    int w = blockIdx.x * 4 + wid;
    float lsum = 0.f, csum = 0.f;
    if (w < Mtot) {
        int node = idx[w];
        float v0 = __bfloat162float(h[(size_t)node * DOUT + lane]);
        float v1 = __bfloat162float(h[(size_t)node * DOUT + 64 + lane]);
        float ps = v0 * u[lane] + v1 * u[64 + lane];
        float p0 = v0 * Wc[lane * 2 + 0] + v1 * Wc[(lane + 64) * 2 + 0];
        float p1 = v0 * Wc[lane * 2 + 1] + v1 * Wc[(lane + 64) * 2 + 1];
#pragma unroll
        for (int o = 32; o > 0; o >>= 1) {
            ps += __shfl_xor(ps, o, 64);
            p0 += __shfl_xor(p0, o, 64);
            p1 += __shfl_xor(p1, o, 64);
        }
        if (lane == 0) {
            float y0 = label[(size_t)node * NCLS + 0];
            float y1 = label[(size_t)node * NCLS + 1];
            lsum = softplusf(-(y0 * ps)) + softplusf(-(y1 * ps));
            float l0 = p0 + bb[0], l1 = p1 + bb[1];
            int pred = (l1 > l0) ? 1 : 0;
            int truth = (y1 > y0) ? 1 : 0;
            csum = (pred == truth) ? 1.f : 0.f;
        }
    }
    if (lane == 0) { sl[wid] = lsum; sc2[wid] = csum; }
    __syncthreads();
    if (threadIdx.x == 0) {
        blockpart[blockIdx.x * 2 + 0] = sl[0] + sl[1] + sl[2] + sl[3];
        blockpart[blockIdx.x * 2 + 1] = sc2[0] + sc2[1] + sc2[2] + sc2[3];
    }
}

__global__ __launch_bounds__(256) void k_final(const float* __restrict__ bp,
                                               float* __restrict__ out, int nb) {
    __shared__ float sl[256], sc2[256];
    int t = threadIdx.x;
    float l = 0.f, c = 0.f;
    for (int i = t; i < nb; i += 256) { l += bp[i * 2]; c += bp[i * 2 + 1]; }
    sl[t] = l; sc2[t] = c;
    __syncthreads();
    for (int o = 128; o > 0; o >>= 1) {
        if (t < o) { sl[t] += sl[t + o]; sc2[t] += sc2[t + o]; }
        __syncthreads();
    }
    if (t == 0) { out[0] = sl[0]; out[1] = sc2[0] * (1.0f / NMASK); }
}

// ---------------- launch ----------------
extern "C" void kernel_launch(void* const* d_in, const int* in_sizes, int n_in,
                              void* d_out, int out_size, void* d_ws, size_t ws_size,
                              hipStream_t stream) {
    const float* x      = (const float*)d_in[0];
    const float* label  = (const float*)d_in[1];
    const int*   idx    = (const int*)d_in[2];
    const int*   src    = (const int*)d_in[3];
    const int*   dst    = (const int*)d_in[4];
    const float* vals   = (const float*)d_in[5];
    const float* h0     = (const float*)d_in[6];
    const float* Ws     = (const float*)d_in[7];
    const float* Vs     = (const float*)d_in[8];
    const float* alphas = (const float*)d_in[9];
    const float* Wc     = (const float*)d_in[10];
    const float* bb     = (const float*)d_in[11];
    const float* u      = (const float*)d_in[12];
    float* out = (float*)d_out;

    char* p = (char*)d_ws;
    __hip_bfloat16* aggcb = (__hip_bfloat16*)p; p += (size_t)N_NODES * DOUT * 2;  // 12.8 MB
    __hip_bfloat16* xb    = (__hip_bfloat16*)p; p += (size_t)N_NODES * DIN * 2;   // 25.6 MB
    unsigned char*  h8    = (unsigned char*)p;  p += (size_t)N_NODES * DOUT;      // 6.4 MB
    uint2*          edh0  = (uint2*)p;          p += (size_t)TE * 8;              // 12 MB
    uint2*          edh1  = (uint2*)p;          p += (size_t)TE * 8;              // 12 MB
    int*            offs  = (int*)p;            p += 200064 * 4;                  // ~0.8 MB
    __hip_bfloat16* WsT   = (__hip_bfloat16*)p; p += (size_t)NHOP * DOUT * DIN * 2;  // 128 KB
    __hip_bfloat16* VsT   = (__hip_bfloat16*)p; p += (size_t)NHOP * DOUT * DOUT * 2; // 64 KB
    float*          blockpart = (float*)p;      p += LOSS_BLOCKS * 2 * 4;         // 20 KB
    // CSR-build scratch aliases xb (xb written by k_cvt AFTER k_bsort; stream-serial)
    uint2* ebkt  = (uint2*)xb;                            // 12 MB
    int*   bh    = (int*)((char*)xb + (size_t)TE * 8);    // 1.15 MB
    int*   sc    = bh + BHN;                              // 1.15 MB
    int*   bsums = sc + BHN;
    // hbf (final bf16 h, 12.8 MB) aliases edh1+offs (dead after hop-2 k_agg)
    __hip_bfloat16* hbf = (__hip_bfloat16*)edh1;

    // bucket-binned CSR build (per-hop prescaled weights; reused for both hops)
    k_bhist<<<NBLKA, 256, 0, stream>>>(dst, bh);
    k_scanA<<<SCANBLKS, SCT, 0, stream>>>(bh, sc, bsums, BHN);
    k_scanB<<<1, SCT, 0, stream>>>(bsums, SCANBLKS);
    k_scanC<<<SCANBLKS, SCT, 0, stream>>>(sc, bsums, BHN);
    k_bbin<<<NBLKA, 256, 0, stream>>>(src, dst, vals, sc, ebkt);
    k_bsort<<<NBUCK, 256, 0, stream>>>(ebkt, sc, alphas, edh0, edh1, offs);

    // conversions: h0 -> fp8 (first gather), x -> bf16 (GEMM A1), weights transposed
    k_cvt8<<<(N_NODES * DOUT / 4 + 255) / 256, 256, 0, stream>>>(h0, h8, N_NODES * DOUT / 4);
    k_cvt<<<(N_NODES * DIN / 2 + 255) / 256, 256, 0, stream>>>(x, xb, N_NODES * DIN / 2);
    k_tw<<<(NHOP * (DIN * DOUT + DOUT * DOUT) + 255) / 256, 256, 0, stream>>>(Ws, Vs, WsT, VsT);

    const int MMBLK = (N_NODES + 127) / 128;  // 391
    // hop 1: gather h0(fp8) -> agg; h1 = sigmoid(x@W0 + agg@V0) -> fp8 only
    k_agg<<<(N_NODES + 3) / 4, 256, 0, stream>>>(h8, edh0, offs, aggcb);
    k_mm<<<MMBLK, 256, 0, stream>>>(xb, WsT, aggcb, VsT, h8, nullptr, N_NODES, DIN, DOUT);
    // hop 2: gather h1(fp8) -> agg; h2 = sigmoid(x@W1 + agg@V1) -> bf16 (for loss)
    k_agg<<<(N_NODES + 3) / 4, 256, 0, stream>>>(h8, edh1, offs, aggcb);
    k_mm<<<MMBLK, 256, 0, stream>>>(xb, WsT + (size_t)DOUT * DIN, aggcb,
                                    VsT + (size_t)DOUT * DOUT, nullptr, hbf,
                                    N_NODES, DIN, DOUT);

    k_loss<<<LOSS_BLOCKS, 256, 0, stream>>>(hbf, label, idx, u, Wc, bb, blockpart, NMASK);
    k_final<<<1, 256, 0, stream>>>(blockpart, out, LOSS_BLOCKS);
}